// Round 9
// baseline (154.031 us; speedup 1.0000x reference)
//
#include <hip/hip_runtime.h>
#include <hip/hip_bf16.h>

typedef short short8 __attribute__((ext_vector_type(8)));
typedef float f32x4 __attribute__((ext_vector_type(4)));
typedef float f32x16 __attribute__((ext_vector_type(16)));
typedef int int4v __attribute__((ext_vector_type(4)));
typedef unsigned short ushort4v __attribute__((ext_vector_type(4)));

#define NB 4
#define NS 4096
#define NE 128
#define ALPHA 0.1275174468f  /* log2(e)/sqrt(128) */
#define KVB 64                 /* keys per staged tile */
#define NIT (NS / KVB)         /* 64 */
#define SPLITS 4               /* 16-key splits sharing one staged tile */

static __device__ __forceinline__ unsigned short f2bf(float f) {
  union { float f; unsigned int u; } v; v.f = f;
  unsigned int u = v.u;
  return (unsigned short)((u + 0x7FFFu + ((u >> 16) & 1u)) >> 16);
}

// compiler-emitted v_cvt_pk_bf16_f32 (RNE, low=a high=b)
static __device__ __forceinline__ unsigned int pack2bf(float a, float b) {
  union { __hip_bfloat162 h; unsigned int u; } v;
  v.h = __float22bfloat162_rn(float2{a, b});
  return v.u;
}

static __device__ __forceinline__ void gload_lds16(const unsigned short* g,
                                                   unsigned short* l) {
  __builtin_amdgcn_global_load_lds(
      (const __attribute__((address_space(1))) unsigned int*)g,
      (__attribute__((address_space(3))) unsigned int*)l, 16, 0, 0);
}

// ---------------------------------------------------------------------------
// Kernel 0: one-time f32 -> bf16 conversion of the three weight matrices.
// ---------------------------------------------------------------------------
__global__ __launch_bounds__(256) void prep_k(
    const float* __restrict__ Wq, const float* __restrict__ Wk,
    const float* __restrict__ Wv,
    unsigned short* __restrict__ Wqb, unsigned short* __restrict__ Wkb,
    unsigned short* __restrict__ Wvb) {
  int i = blockIdx.x * 256 + threadIdx.x;          // 0..12287
  const float* srcs[3] = {Wq, Wk, Wv};
  unsigned short* dsts[3] = {Wqb, Wkb, Wvb};
  int m = i >> 12, off = (i & 4095) * 4;
  float4 v = *(const float4*)(srcs[m] + off);
  ushort4v o;
  o[0] = f2bf(v.x); o[1] = f2bf(v.y); o[2] = f2bf(v.z); o[3] = f2bf(v.w);
  *(ushort4v*)(dsts[m] + off) = o;
}

static __device__ __forceinline__ f32x4 wtile(const short8 xa[4],
                                              const unsigned short* __restrict__ Wb,
                                              int fb, int g, int li) {
  f32x4 acc = {0.f, 0.f, 0.f, 0.f};
  #pragma unroll
  for (int ks = 0; ks < 4; ++ks) {
    short8 wf = *(const short8*)(Wb + (fb * 16 + li) * NE + ks * 32 + g * 8);
    acc = __builtin_amdgcn_mfma_f32_16x16x32_bf16(xa[ks], wf, acc, 0, 0, 0);
  }
  return acc;
}

// ---------------------------------------------------------------------------
// Kernel 1: fused QKV projection (f32 in, bf16 staged out).
// ---------------------------------------------------------------------------
__global__ __launch_bounds__(256) void qkv_proj_k(
    const float* __restrict__ X,
    const unsigned short* __restrict__ Wqb, const float* __restrict__ bq,
    const unsigned short* __restrict__ Wkb, const float* __restrict__ bk,
    const unsigned short* __restrict__ Wvb, const float* __restrict__ bv,
    unsigned short* __restrict__ Qs, unsigned short* __restrict__ Kd,
    unsigned short* __restrict__ VT) {
  const int lane = threadIdx.x & 63;
  const int wv   = threadIdx.x >> 6;
  const int tile = (blockIdx.x >> 1) * 4 + wv;   // 0..1023
  const int fb0  = (blockIdx.x & 1) * 4;         // output half
  const int m0   = tile * 16;
  const int g    = lane >> 4, li = lane & 15;

  short8 xa[4];
  #pragma unroll
  for (int ks = 0; ks < 4; ++ks) {
    const float* xp = X + (size_t)(m0 + li) * NE + ks * 32 + g * 8;
    float4 x0 = *(const float4*)xp;
    float4 x1 = *(const float4*)(xp + 4);
    short8 t;
    t[0] = (short)f2bf(x0.x); t[1] = (short)f2bf(x0.y);
    t[2] = (short)f2bf(x0.z); t[3] = (short)f2bf(x0.w);
    t[4] = (short)f2bf(x1.x); t[5] = (short)f2bf(x1.y);
    t[6] = (short)f2bf(x1.z); t[7] = (short)f2bf(x1.w);
    xa[ks] = t;
  }

  const int bb = m0 >> 12;
  const int n0 = (m0 & 4095) + g * 4;

  #pragma unroll
  for (int f2 = 0; f2 < 4; ++f2) {
    const int fb = fb0 + f2;
    f32x4 aq = wtile(xa, Wqb, fb, g, li);
    float biq = bq[fb * 16 + li];
    #pragma unroll
    for (int r = 0; r < 4; ++r)
      Qs[(size_t)(m0 + g * 4 + r) * NE + fb * 16 + li] = f2bf((aq[r] + biq) * ALPHA);
    f32x4 ak = wtile(xa, Wkb, fb, g, li);
    float bik = bk[fb * 16 + li];
    #pragma unroll
    for (int r = 0; r < 4; ++r)
      Kd[(size_t)(m0 + g * 4 + r) * NE + fb * 16 + li] = f2bf(ak[r] + bik);
    f32x4 av = wtile(xa, Wvb, fb, g, li);
    float biv = bv[fb * 16 + li];
    ushort4v pv;
    #pragma unroll
    for (int r = 0; r < 4; ++r) pv[r] = f2bf(av[r] + biv);
    *(ushort4v*)(VT + (size_t)bb * (NE * NS) + (size_t)(fb * 16 + li) * NS + n0) = pv;
  }
}

// ---------------------------------------------------------------------------
// Kernel 2: flash attention. 512 blocks x 256 threads = 2 blocks/CU.
// Block = 32 q-rows x 4 key-splits. Each wave: 32 q-rows x 16 keys/iter.
// QK = 16x16x32 (K-frags shared across both q-tiles), PV = 32x32x16.
// Counted-vmcnt pipeline (T3/T4): stage tile t+1, wait vmcnt(8) (= tile t
// landed, t+1 in flight), raw barrier, compute, raw barrier. Never drains
// vmcnt to 0 in the main loop. In-LDS 4-split combine at the end.
// ---------------------------------------------------------------------------
__global__ __launch_bounds__(256, 2) void attn_k(
    const unsigned short* __restrict__ Qs, const unsigned short* __restrict__ Kd,
    const unsigned short* __restrict__ VT, float* __restrict__ Out) {
  __shared__ __align__(16) unsigned char lds_raw[66560];
  unsigned short* kb_lds = (unsigned short*)lds_raw;           // [2][8192]
  unsigned short* vb_lds = (unsigned short*)(lds_raw + 32768); // [2][8192]
  float*          smML   = (float*)(lds_raw + 65536);          // [4][64]
  float*          smO    = (float*)lds_raw;                    // [4][4][64][16] alias

  const int lane = threadIdx.x & 63;
  const int wv   = threadIdx.x >> 6;             // split (0..3), stage group, combine et
  const int bi   = blockIdx.x;                   // 0..511
  const int b    = (bi >> 1) & 3;                // batch tied to XCD pair
  const int within = ((bi >> 3) << 1) | (bi & 1);     // 0..127
  const int qb   = within * 32;                  // q-row base (32 rows/block)
  const int g    = lane >> 4, li = lane & 15;
  const int l31  = lane & 31, hi = lane >> 5;
  const bool qsel = (lane >> 4) & 1;             // q-tile of this lane's o-column

  // Q B-frags for both q-tiles: B[k=e][col=q=li]
  short8 qf[2][4];
  #pragma unroll
  for (int qt = 0; qt < 2; ++qt)
    #pragma unroll
    for (int ks = 0; ks < 4; ++ks)
      qf[qt][ks] = *(const short8*)(Qs + (size_t)(b * NS + qb + qt * 16 + li) * NE +
                                    ks * 32 + g * 8);

  const unsigned short* Kb  = Kd + (size_t)b * (NS * NE);
  const unsigned short* VTb = VT + (size_t)b * (NE * NS);

  f32x16 o[4];
  #pragma unroll
  for (int et = 0; et < 4; ++et)
    #pragma unroll
    for (int r = 0; r < 16; ++r) o[et][r] = 0.f;
  float m0 = -1e30f, m1 = -1e30f, L0 = 0.f, L1 = 0.f;

  // P-exchange source lanes
  const int src01 = (lane & 15) | (lane & 32);
  const int src23 = src01 + 16;

  // staging: wave wv loads K groups (jt=wv, ks=0..3) and V groups (et=wv).
  // exactly 8 gload_lds per wave per tile -> vmcnt counting is uniform.
  #define STAGE(BUF, J0)                                                          \
    {                                                                             \
      _Pragma("unroll")                                                           \
      for (int i_ = 0; i_ < 4; ++i_) {                                            \
        gload_lds16(Kb + (size_t)((J0) + wv * 16 + li) * NE + i_ * 32 + g * 8,    \
                    kb_lds + (BUF) * 8192 + (wv * 4 + i_) * 512);                 \
      }                                                                           \
      _Pragma("unroll")                                                           \
      for (int i_ = 0; i_ < 4; ++i_) {                                            \
        gload_lds16(VTb + (size_t)(wv * 32 + l31) * NS + (J0) + i_ * 16 + hi * 8, \
                    vb_lds + (BUF) * 8192 + (wv * 4 + i_) * 512);                 \
      }                                                                           \
    }

  STAGE(0, 0);   // prologue: tile 0 in flight

  #pragma unroll 1
  for (int t = 0; t < NIT; ++t) {
    const int curb = t & 1;
    // stage tile t+1 (wrapped on last iter; data unused) -> 16 outstanding
    STAGE(curb ^ 1, ((t + 1) & (NIT - 1)) * KVB);
    // wait for tile t only (8 newest stay in flight), then rendezvous
    asm volatile("s_waitcnt vmcnt(8)" ::: "memory");
    __builtin_amdgcn_sched_barrier(0);
    __builtin_amdgcn_s_barrier();
    __builtin_amdgcn_sched_barrier(0);

    // ---- QK: 4 shared K-frags (jt=wv), 8 MFMA (2 q-tiles) ----
    f32x4 s0 = {0.f, 0.f, 0.f, 0.f}, s1 = {0.f, 0.f, 0.f, 0.f};
    __builtin_amdgcn_s_setprio(1);
    #pragma unroll
    for (int ks = 0; ks < 4; ++ks) {
      short8 kfr = *(const short8*)(kb_lds + curb * 8192 + (wv * 4 + ks) * 512 + lane * 8);
      s0 = __builtin_amdgcn_mfma_f32_16x16x32_bf16(kfr, qf[0][ks], s0, 0, 0, 0);
      s1 = __builtin_amdgcn_mfma_f32_16x16x32_bf16(kfr, qf[1][ks], s1, 0, 0, 0);
    }
    __builtin_amdgcn_s_setprio(0);
    // lane holds S[q = qt*16 + li][j = t*64 + wv*16 + 4g + r]

    // ---- fresh-max online softmax, per q-tile ----
    float tm0 = fmaxf(fmaxf(s0[0], s0[1]), fmaxf(s0[2], s0[3]));
    float tm1 = fmaxf(fmaxf(s1[0], s1[1]), fmaxf(s1[2], s1[3]));
    tm0 = fmaxf(tm0, __shfl_xor(tm0, 16));
    tm1 = fmaxf(tm1, __shfl_xor(tm1, 16));
    tm0 = fmaxf(tm0, __shfl_xor(tm0, 32));
    tm1 = fmaxf(tm1, __shfl_xor(tm1, 32));
    float mn0 = fmaxf(m0, tm0), c0 = __builtin_amdgcn_exp2f(m0 - mn0); m0 = mn0;
    float mn1 = fmaxf(m1, tm1), c1 = __builtin_amdgcn_exp2f(m1 - mn1); m1 = mn1;
    const float cmy = qsel ? c1 : c0;
    #pragma unroll
    for (int et = 0; et < 4; ++et) o[et] = o[et] * cmy;

    // ---- P = exp2(S - m) <= 1, pack via v_cvt_pk_bf16_f32 ----
    float p00 = __builtin_amdgcn_exp2f(s0[0] - m0);
    float p01 = __builtin_amdgcn_exp2f(s0[1] - m0);
    float p02 = __builtin_amdgcn_exp2f(s0[2] - m0);
    float p03 = __builtin_amdgcn_exp2f(s0[3] - m0);
    float p10 = __builtin_amdgcn_exp2f(s1[0] - m1);
    float p11 = __builtin_amdgcn_exp2f(s1[1] - m1);
    float p12 = __builtin_amdgcn_exp2f(s1[2] - m1);
    float p13 = __builtin_amdgcn_exp2f(s1[3] - m1);
    L0 = L0 * c0 + ((p00 + p01) + (p02 + p03));
    L1 = L1 * c1 + ((p10 + p11) + (p12 + p13));
    unsigned int pk00 = pack2bf(p00, p01);
    unsigned int pk01 = pack2bf(p02, p03);
    unsigned int pk10 = pack2bf(p10, p11);
    unsigned int pk11 = pack2bf(p12, p13);

    // ---- redistribute into PV B-frag (32x32x16): 8 shfl + 4 sel ----
    int ta, tb, w0, w1, w2, w3;
    ta = __shfl((int)pk00, src01); tb = __shfl((int)pk10, src01); w0 = qsel ? tb : ta;
    ta = __shfl((int)pk01, src01); tb = __shfl((int)pk11, src01); w1 = qsel ? tb : ta;
    ta = __shfl((int)pk00, src23); tb = __shfl((int)pk10, src23); w2 = qsel ? tb : ta;
    ta = __shfl((int)pk01, src23); tb = __shfl((int)pk11, src23); w3 = qsel ? tb : ta;
    union { int4v i4; short8 s8; } pb;
    pb.i4 = (int4v){w0, w1, w2, w3};
    // lane holds B[k=j16 = 8*hi + 0..7][col=q = l31]

    // ---- PV: O^T += V^T(32e x 16j) @ P^T(16j x 32q), 4 x mfma 32x32x16 ----
    __builtin_amdgcn_s_setprio(1);
    #pragma unroll
    for (int et = 0; et < 4; ++et) {
      short8 vfr = *(const short8*)(vb_lds + curb * 8192 + (et * 4 + wv) * 512 + lane * 8);
      o[et] = __builtin_amdgcn_mfma_f32_32x32x16_bf16(vfr, pb.s8, o[et], 0, 0, 0);
    }
    __builtin_amdgcn_s_setprio(0);

    // done reading buf[curb]; next iter stages into it
    __builtin_amdgcn_sched_barrier(0);
    __builtin_amdgcn_s_barrier();
    __builtin_amdgcn_sched_barrier(0);
  }

  __syncthreads();   // full drain (wrap-stage) before smO alias reuse

  // ---- epilogue: publish split partials (smO aliases staging region) ----
  L0 += __shfl_xor(L0, 16); L0 += __shfl_xor(L0, 32);
  L1 += __shfl_xor(L1, 16); L1 += __shfl_xor(L1, 32);
  #pragma unroll
  for (int et = 0; et < 4; ++et)
    #pragma unroll
    for (int rq = 0; rq < 4; ++rq) {
      float4 v;
      v.x = o[et][rq * 4 + 0]; v.y = o[et][rq * 4 + 1];
      v.z = o[et][rq * 4 + 2]; v.w = o[et][rq * 4 + 3];
      *(float4*)(smO + (size_t)((wv * 4 + et) * 64 + lane) * 16 + rq * 4) = v;
    }
  if (lane < 16) {
    smML[wv * 64 + lane]      = m0;   // m for q = lane
    smML[wv * 64 + 16 + lane] = m1;   // m for q = 16+lane
    smML[wv * 64 + 32 + lane] = L0;
    smML[wv * 64 + 48 + lane] = L1;
  }
  __syncthreads();

  // ---- combine 4 splits: wave wv handles e-block et=wv ----
  float ms[SPLITS], Ls[SPLITS];
  #pragma unroll
  for (int sp = 0; sp < SPLITS; ++sp) {
    ms[sp] = smML[sp * 64 + l31];
    Ls[sp] = smML[sp * 64 + 32 + l31];
  }
  float M = fmaxf(fmaxf(ms[0], ms[1]), fmaxf(ms[2], ms[3]));
  float W[SPLITS], Ltot = 0.f;
  #pragma unroll
  for (int sp = 0; sp < SPLITS; ++sp) {
    W[sp] = __builtin_amdgcn_exp2f(ms[sp] - M);
    Ltot += W[sp] * Ls[sp];
  }
  const float rL = 1.f / Ltot;
  float* Orow = Out + (size_t)(b * NS + qb + l31) * NE + wv * 32;
  #pragma unroll
  for (int rq = 0; rq < 4; ++rq) {
    float4 acc = make_float4(0.f, 0.f, 0.f, 0.f);
    #pragma unroll
    for (int sp = 0; sp < SPLITS; ++sp) {
      float4 v = *(const float4*)(smO + (size_t)((sp * 4 + wv) * 64 + lane) * 16 + rq * 4);
      acc.x += W[sp] * v.x; acc.y += W[sp] * v.y;
      acc.z += W[sp] * v.z; acc.w += W[sp] * v.w;
    }
    acc.x *= rL; acc.y *= rL; acc.z *= rL; acc.w *= rL;
    // e = wv*32 + 8*rq + 4*hi + 0..3  (C/D row map of 32x32)
    *(float4*)(Orow + 8 * rq + 4 * hi) = acc;
  }
}

extern "C" void kernel_launch(void* const* d_in, const int* in_sizes, int n_in,
                              void* d_out, int out_size, void* d_ws, size_t ws_size,
                              hipStream_t stream) {
  const float* X  = (const float*)d_in[0];
  // d_in[1] = context : unused (per-row bias is softmax-invariant)
  const float* Wq = (const float*)d_in[2];
  const float* bq = (const float*)d_in[3];
  const float* Wk = (const float*)d_in[4];
  const float* bk = (const float*)d_in[5];
  const float* Wv = (const float*)d_in[6];
  const float* bv = (const float*)d_in[7];
  // d_in[8] = Wc, d_in[9] = bc : unused

  unsigned short* Qs  = (unsigned short*)d_ws;                // 4 MB
  unsigned short* Kd  = Qs + (size_t)NB * NS * NE;            // 4 MB
  unsigned short* VT  = Kd + (size_t)NB * NS * NE;            // 4 MB
  unsigned short* Wqb = VT + (size_t)NB * NS * NE;            // 32 KB x3
  unsigned short* Wkb = Wqb + NE * NE;
  unsigned short* Wvb = Wkb + NE * NE;

  prep_k<<<48, 256, 0, stream>>>(Wq, Wk, Wv, Wqb, Wkb, Wvb);
  qkv_proj_k<<<512, 256, 0, stream>>>(X, Wqb, bq, Wkb, bk, Wvb, bv, Qs, Kd, VT);
  attn_k<<<512, 256, 0, stream>>>(Qs, Kd, VT, (float*)d_out);
}

// Round 10
// 115.841 us; speedup vs baseline: 1.3297x; 1.3297x over previous
//
#include <hip/hip_runtime.h>
#include <hip/hip_bf16.h>

typedef short short8 __attribute__((ext_vector_type(8)));
typedef float f32x4 __attribute__((ext_vector_type(4)));
typedef float f32x16 __attribute__((ext_vector_type(16)));
typedef int int4v __attribute__((ext_vector_type(4)));
typedef unsigned short ushort4v __attribute__((ext_vector_type(4)));

#define NB 4
#define NS 4096
#define NE 128
#define ALPHA 0.1275174468f  /* log2(e)/sqrt(128) */
#define KVB 64                 /* keys per staged tile */
#define NIT (NS / KVB)         /* 64 */
#define SPLITS 4               /* 16-key splits sharing one staged tile */

static __device__ __forceinline__ unsigned short f2bf(float f) {
  union { float f; unsigned int u; } v; v.f = f;
  unsigned int u = v.u;
  return (unsigned short)((u + 0x7FFFu + ((u >> 16) & 1u)) >> 16);
}

// compiler-emitted v_cvt_pk_bf16_f32 (RNE, low=a high=b)
static __device__ __forceinline__ unsigned int pack2bf(float a, float b) {
  union { __hip_bfloat162 h; unsigned int u; } v;
  v.h = __float22bfloat162_rn(float2{a, b});
  return v.u;
}

static __device__ __forceinline__ void gload_lds16(const unsigned short* g,
                                                   unsigned short* l) {
  __builtin_amdgcn_global_load_lds(
      (const __attribute__((address_space(1))) unsigned int*)g,
      (__attribute__((address_space(3))) unsigned int*)l, 16, 0, 0);
}

// ---------------------------------------------------------------------------
// Staged layouts in ws (per batch, per 64-key tile, 16 groups x 1KB):
//  K group g=jt*4+ks, lane=gg*16+li_k: K[j=t*64+jt*16+li_k][e=ks*32+gg*8+0..7]
//  V group g=et*4+sp, lane=hi*32+l31 : V[j=t*64+sp*16+hi*8+0..7][e=et*32+l31]
// One gload_lds16 per group = contiguous 1KB burst (lane*16B).
// ---------------------------------------------------------------------------

// ---------------------------------------------------------------------------
// Kernel 0: one-time f32 -> bf16 conversion of the three weight matrices.
// ---------------------------------------------------------------------------
__global__ __launch_bounds__(256) void prep_k(
    const float* __restrict__ Wq, const float* __restrict__ Wk,
    const float* __restrict__ Wv,
    unsigned short* __restrict__ Wqb, unsigned short* __restrict__ Wkb,
    unsigned short* __restrict__ Wvb) {
  int i = blockIdx.x * 256 + threadIdx.x;          // 0..12287
  const float* srcs[3] = {Wq, Wk, Wv};
  unsigned short* dsts[3] = {Wqb, Wkb, Wvb};
  int m = i >> 12, off = (i & 4095) * 4;
  float4 v = *(const float4*)(srcs[m] + off);
  ushort4v o;
  o[0] = f2bf(v.x); o[1] = f2bf(v.y); o[2] = f2bf(v.z); o[3] = f2bf(v.w);
  *(ushort4v*)(dsts[m] + off) = o;
}

static __device__ __forceinline__ f32x4 wtile(const short8 xa[4],
                                              const unsigned short* __restrict__ Wb,
                                              int fb, int g, int li) {
  f32x4 acc = {0.f, 0.f, 0.f, 0.f};
  #pragma unroll
  for (int ks = 0; ks < 4; ++ks) {
    short8 wf = *(const short8*)(Wb + (fb * 16 + li) * NE + ks * 32 + g * 8);
    acc = __builtin_amdgcn_mfma_f32_16x16x32_bf16(xa[ks], wf, acc, 0, 0, 0);
  }
  return acc;
}

// ---------------------------------------------------------------------------
// Kernel 1: fused QKV projection (f32 in; Q row-major, K/V in staged layout).
// ---------------------------------------------------------------------------
__global__ __launch_bounds__(256) void qkv_proj_k(
    const float* __restrict__ X,
    const unsigned short* __restrict__ Wqb, const float* __restrict__ bq,
    const unsigned short* __restrict__ Wkb, const float* __restrict__ bk,
    const unsigned short* __restrict__ Wvb, const float* __restrict__ bv,
    unsigned short* __restrict__ Qs, unsigned short* __restrict__ Kd,
    unsigned short* __restrict__ VT) {
  const int lane = threadIdx.x & 63;
  const int wv   = threadIdx.x >> 6;
  const int tile = (blockIdx.x >> 1) * 4 + wv;   // 0..1023
  const int fb0  = (blockIdx.x & 1) * 4;         // output half
  const int m0   = tile * 16;
  const int g    = lane >> 4, li = lane & 15;

  short8 xa[4];
  #pragma unroll
  for (int ks = 0; ks < 4; ++ks) {
    const float* xp = X + (size_t)(m0 + li) * NE + ks * 32 + g * 8;
    float4 x0 = *(const float4*)xp;
    float4 x1 = *(const float4*)(xp + 4);
    short8 t;
    t[0] = (short)f2bf(x0.x); t[1] = (short)f2bf(x0.y);
    t[2] = (short)f2bf(x0.z); t[3] = (short)f2bf(x0.w);
    t[4] = (short)f2bf(x1.x); t[5] = (short)f2bf(x1.y);
    t[6] = (short)f2bf(x1.z); t[7] = (short)f2bf(x1.w);
    xa[ks] = t;
  }

  const int bb  = m0 >> 12;              // batch
  const int tT  = (m0 & 4095) >> 6;      // 64-key tile within batch
  const int jtT = (m0 >> 4) & 3;         // 16-key subtile (= sp for V)
  const size_t tgbase = ((size_t)(bb * 64 + tT)) * 16;   // group base (x512)

  #pragma unroll
  for (int f2 = 0; f2 < 4; ++f2) {
    const int fb = fb0 + f2;
    // ---- Q (row-major, exp2 units) ----
    f32x4 aq = wtile(xa, Wqb, fb, g, li);
    float biq = bq[fb * 16 + li];
    #pragma unroll
    for (int r = 0; r < 4; ++r)
      Qs[(size_t)(m0 + g * 4 + r) * NE + fb * 16 + li] = f2bf((aq[r] + biq) * ALPHA);
    // ---- K staged: group jt*4+ks, in-group (gg*16 + li_k)*8 + e' ----
    f32x4 ak = wtile(xa, Wkb, fb, g, li);
    float bik = bk[fb * 16 + li];
    unsigned short* kdst = Kd + (tgbase + jtT * 4 + (fb >> 1)) * 512 +
                           ((fb & 1) * 2 + (li >> 3)) * 128 + (li & 7);
    #pragma unroll
    for (int r = 0; r < 4; ++r)
      kdst[(g * 4 + r) * 8] = f2bf(ak[r] + bik);
    // ---- V staged: group et*4+sp, in-group (hi*32 + l31)*8 + k7 ----
    f32x4 av = wtile(xa, Wvb, fb, g, li);
    float biv = bv[fb * 16 + li];
    ushort4v pv;
    #pragma unroll
    for (int r = 0; r < 4; ++r) pv[r] = f2bf(av[r] + biv);
    *(ushort4v*)(VT + (tgbase + (fb >> 1) * 4 + jtT) * 512 +
                 ((g >> 1) * 32 + (fb & 1) * 16 + li) * 8 + (g & 1) * 4) = pv;
  }
}

// ---------------------------------------------------------------------------
// Kernel 2: flash attention. 512 blocks x 256 threads = 2 blocks/CU.
// Block = 32 q-rows x 4 key-splits. Each wave: 32 q-rows x 16 keys/iter.
// QK = 16x16x32 (K-frags shared across both q-tiles), PV = 32x32x16.
// Staging now reads the pre-swizzled layout: each gload_lds16 is a linear
// 1KB burst (4x fewer L2 line requests). Counted-vmcnt pipeline kept.
// ---------------------------------------------------------------------------
__global__ __launch_bounds__(256, 2) void attn_k(
    const unsigned short* __restrict__ Qs, const unsigned short* __restrict__ Kd,
    const unsigned short* __restrict__ VT, float* __restrict__ Out) {
  __shared__ __align__(16) unsigned char lds_raw[66560];
  unsigned short* kb_lds = (unsigned short*)lds_raw;           // [2][8192]
  unsigned short* vb_lds = (unsigned short*)(lds_raw + 32768); // [2][8192]
  float*          smML   = (float*)(lds_raw + 65536);          // [4][64]
  float*          smO    = (float*)lds_raw;                    // [4][4][64][16] alias

  const int lane = threadIdx.x & 63;
  const int wv   = threadIdx.x >> 6;             // split (0..3), stage group, combine et
  const int bi   = blockIdx.x;                   // 0..511
  const int b    = (bi >> 1) & 3;                // batch tied to XCD pair
  const int within = ((bi >> 3) << 1) | (bi & 1);     // 0..127
  const int qb   = within * 32;                  // q-row base (32 rows/block)
  const int g    = lane >> 4, li = lane & 15;
  const int l31  = lane & 31, hi = lane >> 5;
  const bool qsel = (lane >> 4) & 1;             // q-tile of this lane's o-column

  // Q B-frags for both q-tiles: B[k=e][col=q=li]
  short8 qf[2][4];
  #pragma unroll
  for (int qt = 0; qt < 2; ++qt)
    #pragma unroll
    for (int ks = 0; ks < 4; ++ks)
      qf[qt][ks] = *(const short8*)(Qs + (size_t)(b * NS + qb + qt * 16 + li) * NE +
                                    ks * 32 + g * 8);

  const size_t stbase = (size_t)b * 64 * 16 * 512;   // staged base (shorts)

  f32x16 o[4];
  #pragma unroll
  for (int et = 0; et < 4; ++et)
    #pragma unroll
    for (int r = 0; r < 16; ++r) o[et][r] = 0.f;
  float m0 = -1e30f, m1 = -1e30f, L0 = 0.f, L1 = 0.f;

  // P-exchange source lanes
  const int src01 = (lane & 15) | (lane & 32);
  const int src23 = src01 + 16;

  // staging: wave wv loads K groups wv*4+i_ and V groups wv*4+i_ of tile T.
  // Source is contiguous: group base + lane*16B. 8 gloads per wave per tile.
  #define STAGE(BUF, T)                                                         \
    {                                                                           \
      _Pragma("unroll")                                                         \
      for (int i_ = 0; i_ < 4; ++i_) {                                          \
        gload_lds16(Kd + stbase + ((size_t)(T) * 16 + wv * 4 + i_) * 512 + lane * 8, \
                    kb_lds + (BUF) * 8192 + (wv * 4 + i_) * 512);               \
      }                                                                         \
      _Pragma("unroll")                                                         \
      for (int i_ = 0; i_ < 4; ++i_) {                                          \
        gload_lds16(VT + stbase + ((size_t)(T) * 16 + wv * 4 + i_) * 512 + lane * 8, \
                    vb_lds + (BUF) * 8192 + (wv * 4 + i_) * 512);               \
      }                                                                         \
    }

  STAGE(0, 0);   // prologue: tile 0 in flight

  #pragma unroll 1
  for (int t = 0; t < NIT; ++t) {
    const int curb = t & 1;
    // stage tile t+1 (wrapped on last iter; data unused) -> 16 outstanding
    STAGE(curb ^ 1, (t + 1) & (NIT - 1));
    // wait for tile t only (8 newest stay in flight), then rendezvous
    asm volatile("s_waitcnt vmcnt(8)" ::: "memory");
    __builtin_amdgcn_sched_barrier(0);
    __builtin_amdgcn_s_barrier();
    __builtin_amdgcn_sched_barrier(0);

    // ---- QK: 4 shared K-frags (jt=wv), 8 MFMA (2 q-tiles) ----
    f32x4 s0 = {0.f, 0.f, 0.f, 0.f}, s1 = {0.f, 0.f, 0.f, 0.f};
    __builtin_amdgcn_s_setprio(1);
    #pragma unroll
    for (int ks = 0; ks < 4; ++ks) {
      short8 kfr = *(const short8*)(kb_lds + curb * 8192 + (wv * 4 + ks) * 512 + lane * 8);
      s0 = __builtin_amdgcn_mfma_f32_16x16x32_bf16(kfr, qf[0][ks], s0, 0, 0, 0);
      s1 = __builtin_amdgcn_mfma_f32_16x16x32_bf16(kfr, qf[1][ks], s1, 0, 0, 0);
    }
    __builtin_amdgcn_s_setprio(0);
    // lane holds S[q = qt*16 + li][j = t*64 + wv*16 + 4g + r]

    // ---- fresh-max online softmax, per q-tile ----
    float tm0 = fmaxf(fmaxf(s0[0], s0[1]), fmaxf(s0[2], s0[3]));
    float tm1 = fmaxf(fmaxf(s1[0], s1[1]), fmaxf(s1[2], s1[3]));
    tm0 = fmaxf(tm0, __shfl_xor(tm0, 16));
    tm1 = fmaxf(tm1, __shfl_xor(tm1, 16));
    tm0 = fmaxf(tm0, __shfl_xor(tm0, 32));
    tm1 = fmaxf(tm1, __shfl_xor(tm1, 32));
    float mn0 = fmaxf(m0, tm0), c0 = __builtin_amdgcn_exp2f(m0 - mn0); m0 = mn0;
    float mn1 = fmaxf(m1, tm1), c1 = __builtin_amdgcn_exp2f(m1 - mn1); m1 = mn1;
    const float cmy = qsel ? c1 : c0;
    #pragma unroll
    for (int et = 0; et < 4; ++et) o[et] = o[et] * cmy;

    // ---- P = exp2(S - m) <= 1, pack via v_cvt_pk_bf16_f32 ----
    float p00 = __builtin_amdgcn_exp2f(s0[0] - m0);
    float p01 = __builtin_amdgcn_exp2f(s0[1] - m0);
    float p02 = __builtin_amdgcn_exp2f(s0[2] - m0);
    float p03 = __builtin_amdgcn_exp2f(s0[3] - m0);
    float p10 = __builtin_amdgcn_exp2f(s1[0] - m1);
    float p11 = __builtin_amdgcn_exp2f(s1[1] - m1);
    float p12 = __builtin_amdgcn_exp2f(s1[2] - m1);
    float p13 = __builtin_amdgcn_exp2f(s1[3] - m1);
    L0 = L0 * c0 + ((p00 + p01) + (p02 + p03));
    L1 = L1 * c1 + ((p10 + p11) + (p12 + p13));
    unsigned int pk00 = pack2bf(p00, p01);
    unsigned int pk01 = pack2bf(p02, p03);
    unsigned int pk10 = pack2bf(p10, p11);
    unsigned int pk11 = pack2bf(p12, p13);

    // ---- redistribute into PV B-frag (32x32x16): 8 shfl + 4 sel ----
    int ta, tb, w0, w1, w2, w3;
    ta = __shfl((int)pk00, src01); tb = __shfl((int)pk10, src01); w0 = qsel ? tb : ta;
    ta = __shfl((int)pk01, src01); tb = __shfl((int)pk11, src01); w1 = qsel ? tb : ta;
    ta = __shfl((int)pk00, src23); tb = __shfl((int)pk10, src23); w2 = qsel ? tb : ta;
    ta = __shfl((int)pk01, src23); tb = __shfl((int)pk11, src23); w3 = qsel ? tb : ta;
    union { int4v i4; short8 s8; } pb;
    pb.i4 = (int4v){w0, w1, w2, w3};
    // lane holds B[k=j16 = 8*hi + 0..7][col=q = l31]

    // ---- PV: O^T += V^T(32e x 16j) @ P^T(16j x 32q), 4 x mfma 32x32x16 ----
    __builtin_amdgcn_s_setprio(1);
    #pragma unroll
    for (int et = 0; et < 4; ++et) {
      short8 vfr = *(const short8*)(vb_lds + curb * 8192 + (et * 4 + wv) * 512 + lane * 8);
      o[et] = __builtin_amdgcn_mfma_f32_32x32x16_bf16(vfr, pb.s8, o[et], 0, 0, 0);
    }
    __builtin_amdgcn_s_setprio(0);

    // done reading buf[curb]; next iter stages into it
    __builtin_amdgcn_sched_barrier(0);
    __builtin_amdgcn_s_barrier();
    __builtin_amdgcn_sched_barrier(0);
  }

  __syncthreads();   // full drain (wrap-stage) before smO alias reuse

  // ---- epilogue: publish split partials (smO aliases staging region) ----
  L0 += __shfl_xor(L0, 16); L0 += __shfl_xor(L0, 32);
  L1 += __shfl_xor(L1, 16); L1 += __shfl_xor(L1, 32);
  #pragma unroll
  for (int et = 0; et < 4; ++et)
    #pragma unroll
    for (int rq = 0; rq < 4; ++rq) {
      float4 v;
      v.x = o[et][rq * 4 + 0]; v.y = o[et][rq * 4 + 1];
      v.z = o[et][rq * 4 + 2]; v.w = o[et][rq * 4 + 3];
      *(float4*)(smO + (size_t)((wv * 4 + et) * 64 + lane) * 16 + rq * 4) = v;
    }
  if (lane < 16) {
    smML[wv * 64 + lane]      = m0;   // m for q = lane
    smML[wv * 64 + 16 + lane] = m1;   // m for q = 16+lane
    smML[wv * 64 + 32 + lane] = L0;
    smML[wv * 64 + 48 + lane] = L1;
  }
  __syncthreads();

  // ---- combine 4 splits: wave wv handles e-block et=wv ----
  float ms[SPLITS], Ls[SPLITS];
  #pragma unroll
  for (int sp = 0; sp < SPLITS; ++sp) {
    ms[sp] = smML[sp * 64 + l31];
    Ls[sp] = smML[sp * 64 + 32 + l31];
  }
  float M = fmaxf(fmaxf(ms[0], ms[1]), fmaxf(ms[2], ms[3]));
  float W[SPLITS], Ltot = 0.f;
  #pragma unroll
  for (int sp = 0; sp < SPLITS; ++sp) {
    W[sp] = __builtin_amdgcn_exp2f(ms[sp] - M);
    Ltot += W[sp] * Ls[sp];
  }
  const float rL = 1.f / Ltot;
  float* Orow = Out + (size_t)(b * NS + qb + l31) * NE + wv * 32;
  #pragma unroll
  for (int rq = 0; rq < 4; ++rq) {
    float4 acc = make_float4(0.f, 0.f, 0.f, 0.f);
    #pragma unroll
    for (int sp = 0; sp < SPLITS; ++sp) {
      float4 v = *(const float4*)(smO + (size_t)((sp * 4 + wv) * 64 + lane) * 16 + rq * 4);
      acc.x += W[sp] * v.x; acc.y += W[sp] * v.y;
      acc.z += W[sp] * v.z; acc.w += W[sp] * v.w;
    }
    acc.x *= rL; acc.y *= rL; acc.z *= rL; acc.w *= rL;
    // e = wv*32 + 8*rq + 4*hi + 0..3  (C/D row map of 32x32)
    *(float4*)(Orow + 8 * rq + 4 * hi) = acc;
  }
}

extern "C" void kernel_launch(void* const* d_in, const int* in_sizes, int n_in,
                              void* d_out, int out_size, void* d_ws, size_t ws_size,
                              hipStream_t stream) {
  const float* X  = (const float*)d_in[0];
  // d_in[1] = context : unused (per-row bias is softmax-invariant)
  const float* Wq = (const float*)d_in[2];
  const float* bq = (const float*)d_in[3];
  const float* Wk = (const float*)d_in[4];
  const float* bk = (const float*)d_in[5];
  const float* Wv = (const float*)d_in[6];
  const float* bv = (const float*)d_in[7];
  // d_in[8] = Wc, d_in[9] = bc : unused

  unsigned short* Qs  = (unsigned short*)d_ws;                // 4 MB
  unsigned short* Kd  = Qs + (size_t)NB * NS * NE;            // 4 MB (staged)
  unsigned short* VT  = Kd + (size_t)NB * NS * NE;            // 4 MB (staged)
  unsigned short* Wqb = VT + (size_t)NB * NS * NE;            // 32 KB x3
  unsigned short* Wkb = Wqb + NE * NE;
  unsigned short* Wvb = Wkb + NE * NE;

  prep_k<<<48, 256, 0, stream>>>(Wq, Wk, Wv, Wqb, Wkb, Wvb);
  qkv_proj_k<<<512, 256, 0, stream>>>(X, Wqb, bq, Wkb, bk, Wvb, bv, Qs, Kd, VT);
  attn_k<<<512, 256, 0, stream>>>(Qs, Kd, VT, (float*)d_out);
}

// Round 11
// 112.301 us; speedup vs baseline: 1.3716x; 1.0315x over previous
//
#include <hip/hip_runtime.h>
#include <hip/hip_bf16.h>

typedef short short8 __attribute__((ext_vector_type(8)));
typedef float f32x4 __attribute__((ext_vector_type(4)));
typedef float f32x16 __attribute__((ext_vector_type(16)));
typedef int int4v __attribute__((ext_vector_type(4)));
typedef unsigned short ushort4v __attribute__((ext_vector_type(4)));

#define NB 4
#define NS 4096
#define NE 128
#define ALPHA 0.1275174468f  /* log2(e)/sqrt(128) */
#define KVB 64                 /* keys per staged tile */
#define NIT (NS / KVB)         /* 64 */
#define SPLITS 4               /* 16-key splits sharing one staged tile */

static __device__ __forceinline__ unsigned short f2bf(float f) {
  union { float f; unsigned int u; } v; v.f = f;
  unsigned int u = v.u;
  return (unsigned short)((u + 0x7FFFu + ((u >> 16) & 1u)) >> 16);
}

// compiler-emitted v_cvt_pk_bf16_f32 (RNE, low=a high=b)
static __device__ __forceinline__ unsigned int pack2bf(float a, float b) {
  union { __hip_bfloat162 h; unsigned int u; } v;
  v.h = __float22bfloat162_rn(float2{a, b});
  return v.u;
}

static __device__ __forceinline__ void gload_lds16(const unsigned short* g,
                                                   unsigned short* l) {
  __builtin_amdgcn_global_load_lds(
      (const __attribute__((address_space(1))) unsigned int*)g,
      (__attribute__((address_space(3))) unsigned int*)l, 16, 0, 0);
}

// ---------------------------------------------------------------------------
// Staged layouts in ws (per batch, per 64-key tile, 16 groups x 1KB):
//  K group g=jt*4+ks, lane=gg*16+li_k: K[j=t*64+jt*16+li_k][e=ks*32+gg*8+0..7]
//  V group g=et*4+sp, lane=hi*32+l31 : V[j=t*64+sp*16+hi*8+0..7][e=et*32+l31]
// One gload_lds16 per group = contiguous 1KB burst (lane*16B).
// ---------------------------------------------------------------------------

// ---------------------------------------------------------------------------
// Kernel 0: one-time f32 -> bf16 conversion of the three weight matrices.
// ---------------------------------------------------------------------------
__global__ __launch_bounds__(256) void prep_k(
    const float* __restrict__ Wq, const float* __restrict__ Wk,
    const float* __restrict__ Wv,
    unsigned short* __restrict__ Wqb, unsigned short* __restrict__ Wkb,
    unsigned short* __restrict__ Wvb) {
  int i = blockIdx.x * 256 + threadIdx.x;          // 0..12287
  const float* srcs[3] = {Wq, Wk, Wv};
  unsigned short* dsts[3] = {Wqb, Wkb, Wvb};
  int m = i >> 12, off = (i & 4095) * 4;
  float4 v = *(const float4*)(srcs[m] + off);
  ushort4v o;
  o[0] = f2bf(v.x); o[1] = f2bf(v.y); o[2] = f2bf(v.z); o[3] = f2bf(v.w);
  *(ushort4v*)(dsts[m] + off) = o;
}

static __device__ __forceinline__ f32x4 wtile(const short8 xa[4],
                                              const unsigned short* __restrict__ Wb,
                                              int fb, int g, int li) {
  f32x4 acc = {0.f, 0.f, 0.f, 0.f};
  #pragma unroll
  for (int ks = 0; ks < 4; ++ks) {
    short8 wf = *(const short8*)(Wb + (fb * 16 + li) * NE + ks * 32 + g * 8);
    acc = __builtin_amdgcn_mfma_f32_16x16x32_bf16(xa[ks], wf, acc, 0, 0, 0);
  }
  return acc;
}

// ---------------------------------------------------------------------------
// Kernel 1: fused QKV projection (f32 in; Q row-major, K/V in staged layout).
// ---------------------------------------------------------------------------
__global__ __launch_bounds__(256) void qkv_proj_k(
    const float* __restrict__ X,
    const unsigned short* __restrict__ Wqb, const float* __restrict__ bq,
    const unsigned short* __restrict__ Wkb, const float* __restrict__ bk,
    const unsigned short* __restrict__ Wvb, const float* __restrict__ bv,
    unsigned short* __restrict__ Qs, unsigned short* __restrict__ Kd,
    unsigned short* __restrict__ VT) {
  const int lane = threadIdx.x & 63;
  const int wv   = threadIdx.x >> 6;
  const int tile = (blockIdx.x >> 1) * 4 + wv;   // 0..1023
  const int fb0  = (blockIdx.x & 1) * 4;         // output half
  const int m0   = tile * 16;
  const int g    = lane >> 4, li = lane & 15;

  short8 xa[4];
  #pragma unroll
  for (int ks = 0; ks < 4; ++ks) {
    const float* xp = X + (size_t)(m0 + li) * NE + ks * 32 + g * 8;
    float4 x0 = *(const float4*)xp;
    float4 x1 = *(const float4*)(xp + 4);
    short8 t;
    t[0] = (short)f2bf(x0.x); t[1] = (short)f2bf(x0.y);
    t[2] = (short)f2bf(x0.z); t[3] = (short)f2bf(x0.w);
    t[4] = (short)f2bf(x1.x); t[5] = (short)f2bf(x1.y);
    t[6] = (short)f2bf(x1.z); t[7] = (short)f2bf(x1.w);
    xa[ks] = t;
  }

  const int bb  = m0 >> 12;              // batch
  const int tT  = (m0 & 4095) >> 6;      // 64-key tile within batch
  const int jtT = (m0 >> 4) & 3;         // 16-key subtile (= sp for V)
  const size_t tgbase = ((size_t)(bb * 64 + tT)) * 16;   // group base (x512)

  #pragma unroll
  for (int f2 = 0; f2 < 4; ++f2) {
    const int fb = fb0 + f2;
    // ---- Q (row-major, exp2 units) ----
    f32x4 aq = wtile(xa, Wqb, fb, g, li);
    float biq = bq[fb * 16 + li];
    #pragma unroll
    for (int r = 0; r < 4; ++r)
      Qs[(size_t)(m0 + g * 4 + r) * NE + fb * 16 + li] = f2bf((aq[r] + biq) * ALPHA);
    // ---- K staged: group jt*4+ks, in-group (gg*16 + li_k)*8 + e' ----
    f32x4 ak = wtile(xa, Wkb, fb, g, li);
    float bik = bk[fb * 16 + li];
    unsigned short* kdst = Kd + (tgbase + jtT * 4 + (fb >> 1)) * 512 +
                           ((fb & 1) * 2 + (li >> 3)) * 128 + (li & 7);
    #pragma unroll
    for (int r = 0; r < 4; ++r)
      kdst[(g * 4 + r) * 8] = f2bf(ak[r] + bik);
    // ---- V staged: group et*4+sp, in-group (hi*32 + l31)*8 + k7 ----
    f32x4 av = wtile(xa, Wvb, fb, g, li);
    float biv = bv[fb * 16 + li];
    ushort4v pv;
    #pragma unroll
    for (int r = 0; r < 4; ++r) pv[r] = f2bf(av[r] + biv);
    *(ushort4v*)(VT + (tgbase + (fb >> 1) * 4 + jtT) * 512 +
                 ((g >> 1) * 32 + (fb & 1) * 16 + li) * 8 + (g & 1) * 4) = pv;
  }
}

// ---------------------------------------------------------------------------
// Kernel 2: flash attention. 512 blocks x 256 threads = 2 blocks/CU.
// Block = 32 q-rows x 4 key-splits. Each wave: 32 q-rows x 16 keys/iter.
// BARRIER-FREE main loop: each wave stages exactly the 8 x 1KB groups it
// consumes (K groups wv*4+i, V groups i*4+wv), waits its OWN vmcnt(8), and
// never touches another wave's LDS region. Waves drift freely; the only
// block sync is the final combine. Counted-vmcnt 2-deep pipeline kept.
// ---------------------------------------------------------------------------
__global__ __launch_bounds__(256, 2) void attn_k(
    const unsigned short* __restrict__ Qs, const unsigned short* __restrict__ Kd,
    const unsigned short* __restrict__ VT, float* __restrict__ Out) {
  __shared__ __align__(16) unsigned char lds_raw[66560];
  unsigned short* kb_lds = (unsigned short*)lds_raw;           // [2][8192]
  unsigned short* vb_lds = (unsigned short*)(lds_raw + 32768); // [2][8192]
  float*          smML   = (float*)(lds_raw + 65536);          // [4][64]
  float*          smO    = (float*)lds_raw;                    // [4][4][64][16] alias

  const int lane = threadIdx.x & 63;
  const int wv   = threadIdx.x >> 6;             // split (0..3), stage group, combine et
  const int bi   = blockIdx.x;                   // 0..511
  const int b    = (bi >> 1) & 3;                // batch tied to XCD pair
  const int within = ((bi >> 3) << 1) | (bi & 1);     // 0..127
  const int qb   = within * 32;                  // q-row base (32 rows/block)
  const int g    = lane >> 4, li = lane & 15;
  const int l31  = lane & 31, hi = lane >> 5;
  const bool qsel = (lane >> 4) & 1;             // q-tile of this lane's o-column

  // Q B-frags for both q-tiles: B[k=e][col=q=li]
  short8 qf[2][4];
  #pragma unroll
  for (int qt = 0; qt < 2; ++qt)
    #pragma unroll
    for (int ks = 0; ks < 4; ++ks)
      qf[qt][ks] = *(const short8*)(Qs + (size_t)(b * NS + qb + qt * 16 + li) * NE +
                                    ks * 32 + g * 8);

  const size_t stbase = (size_t)b * 64 * 16 * 512;   // staged base (shorts)

  f32x16 o[4];
  #pragma unroll
  for (int et = 0; et < 4; ++et)
    #pragma unroll
    for (int r = 0; r < 16; ++r) o[et][r] = 0.f;
  float m0 = -1e30f, m1 = -1e30f, L0 = 0.f, L1 = 0.f;

  // P-exchange source lanes
  const int src01 = (lane & 15) | (lane & 32);
  const int src23 = src01 + 16;

  // staging: wave wv stages EXACTLY what it consumes:
  //   K groups wv*4+i_  (QK reads kb group wv*4+ks)
  //   V groups i_*4+wv  (PV reads vb group et*4+wv)
  // 8 gloads per wave per tile; contiguous 1KB bursts; wave-private regions.
  #define STAGE(BUF, T)                                                         \
    {                                                                           \
      _Pragma("unroll")                                                         \
      for (int i_ = 0; i_ < 4; ++i_) {                                          \
        gload_lds16(Kd + stbase + ((size_t)(T) * 16 + wv * 4 + i_) * 512 + lane * 8, \
                    kb_lds + (BUF) * 8192 + (wv * 4 + i_) * 512);               \
      }                                                                         \
      _Pragma("unroll")                                                         \
      for (int i_ = 0; i_ < 4; ++i_) {                                          \
        gload_lds16(VT + stbase + ((size_t)(T) * 16 + i_ * 4 + wv) * 512 + lane * 8, \
                    vb_lds + (BUF) * 8192 + (i_ * 4 + wv) * 512);               \
      }                                                                         \
    }

  STAGE(0, 0);   // prologue: tile 0 in flight

  #pragma unroll 1
  for (int t = 0; t < NIT; ++t) {
    const int curb = t & 1;
    // stage tile t+1 (wrapped on last iter; data unused) -> 16 outstanding
    __builtin_amdgcn_sched_barrier(0);
    STAGE(curb ^ 1, (t + 1) & (NIT - 1));
    // wait for own tile t loads only (8 newest stay in flight). No barrier.
    asm volatile("s_waitcnt vmcnt(8)" ::: "memory");
    __builtin_amdgcn_sched_barrier(0);

    // ---- QK: 4 own K-frags (jt=wv), 8 MFMA (2 q-tiles) ----
    f32x4 s0 = {0.f, 0.f, 0.f, 0.f}, s1 = {0.f, 0.f, 0.f, 0.f};
    __builtin_amdgcn_s_setprio(1);
    #pragma unroll
    for (int ks = 0; ks < 4; ++ks) {
      short8 kfr = *(const short8*)(kb_lds + curb * 8192 + (wv * 4 + ks) * 512 + lane * 8);
      s0 = __builtin_amdgcn_mfma_f32_16x16x32_bf16(kfr, qf[0][ks], s0, 0, 0, 0);
      s1 = __builtin_amdgcn_mfma_f32_16x16x32_bf16(kfr, qf[1][ks], s1, 0, 0, 0);
    }
    __builtin_amdgcn_s_setprio(0);
    // lane holds S[q = qt*16 + li][j = t*64 + wv*16 + 4g + r]

    // ---- fresh-max online softmax, per q-tile ----
    float tm0 = fmaxf(fmaxf(s0[0], s0[1]), fmaxf(s0[2], s0[3]));
    float tm1 = fmaxf(fmaxf(s1[0], s1[1]), fmaxf(s1[2], s1[3]));
    tm0 = fmaxf(tm0, __shfl_xor(tm0, 16));
    tm1 = fmaxf(tm1, __shfl_xor(tm1, 16));
    tm0 = fmaxf(tm0, __shfl_xor(tm0, 32));
    tm1 = fmaxf(tm1, __shfl_xor(tm1, 32));
    float mn0 = fmaxf(m0, tm0), c0 = __builtin_amdgcn_exp2f(m0 - mn0); m0 = mn0;
    float mn1 = fmaxf(m1, tm1), c1 = __builtin_amdgcn_exp2f(m1 - mn1); m1 = mn1;
    const float cmy = qsel ? c1 : c0;
    #pragma unroll
    for (int et = 0; et < 4; ++et) o[et] = o[et] * cmy;

    // ---- P = exp2(S - m) <= 1, pack via v_cvt_pk_bf16_f32 ----
    float p00 = __builtin_amdgcn_exp2f(s0[0] - m0);
    float p01 = __builtin_amdgcn_exp2f(s0[1] - m0);
    float p02 = __builtin_amdgcn_exp2f(s0[2] - m0);
    float p03 = __builtin_amdgcn_exp2f(s0[3] - m0);
    float p10 = __builtin_amdgcn_exp2f(s1[0] - m1);
    float p11 = __builtin_amdgcn_exp2f(s1[1] - m1);
    float p12 = __builtin_amdgcn_exp2f(s1[2] - m1);
    float p13 = __builtin_amdgcn_exp2f(s1[3] - m1);
    L0 = L0 * c0 + ((p00 + p01) + (p02 + p03));
    L1 = L1 * c1 + ((p10 + p11) + (p12 + p13));
    unsigned int pk00 = pack2bf(p00, p01);
    unsigned int pk01 = pack2bf(p02, p03);
    unsigned int pk10 = pack2bf(p10, p11);
    unsigned int pk11 = pack2bf(p12, p13);

    // ---- redistribute into PV B-frag (32x32x16): 8 shfl + 4 sel ----
    int ta, tb, w0, w1, w2, w3;
    ta = __shfl((int)pk00, src01); tb = __shfl((int)pk10, src01); w0 = qsel ? tb : ta;
    ta = __shfl((int)pk01, src01); tb = __shfl((int)pk11, src01); w1 = qsel ? tb : ta;
    ta = __shfl((int)pk00, src23); tb = __shfl((int)pk10, src23); w2 = qsel ? tb : ta;
    ta = __shfl((int)pk01, src23); tb = __shfl((int)pk11, src23); w3 = qsel ? tb : ta;
    union { int4v i4; short8 s8; } pb;
    pb.i4 = (int4v){w0, w1, w2, w3};
    // lane holds B[k=j16 = 8*hi + 0..7][col=q = l31]

    // ---- PV: O^T += V^T(32e x 16j) @ P^T(16j x 32q), 4 x mfma 32x32x16 ----
    __builtin_amdgcn_s_setprio(1);
    #pragma unroll
    for (int et = 0; et < 4; ++et) {
      short8 vfr = *(const short8*)(vb_lds + curb * 8192 + (et * 4 + wv) * 512 + lane * 8);
      o[et] = __builtin_amdgcn_mfma_f32_32x32x16_bf16(vfr, pb.s8, o[et], 0, 0, 0);
    }
    __builtin_amdgcn_s_setprio(0);
    // no barrier: next iter stages into buf[curb], which only THIS wave reads
  }

  __syncthreads();   // full drain (wrap-stage) before smO alias reuse

  // ---- epilogue: publish split partials (smO aliases staging region) ----
  L0 += __shfl_xor(L0, 16); L0 += __shfl_xor(L0, 32);
  L1 += __shfl_xor(L1, 16); L1 += __shfl_xor(L1, 32);
  #pragma unroll
  for (int et = 0; et < 4; ++et)
    #pragma unroll
    for (int rq = 0; rq < 4; ++rq) {
      float4 v;
      v.x = o[et][rq * 4 + 0]; v.y = o[et][rq * 4 + 1];
      v.z = o[et][rq * 4 + 2]; v.w = o[et][rq * 4 + 3];
      *(float4*)(smO + (size_t)((wv * 4 + et) * 64 + lane) * 16 + rq * 4) = v;
    }
  if (lane < 16) {
    smML[wv * 64 + lane]      = m0;   // m for q = lane
    smML[wv * 64 + 16 + lane] = m1;   // m for q = 16+lane
    smML[wv * 64 + 32 + lane] = L0;
    smML[wv * 64 + 48 + lane] = L1;
  }
  __syncthreads();

  // ---- combine 4 splits: wave wv handles e-block et=wv ----
  float ms[SPLITS], Ls[SPLITS];
  #pragma unroll
  for (int sp = 0; sp < SPLITS; ++sp) {
    ms[sp] = smML[sp * 64 + l31];
    Ls[sp] = smML[sp * 64 + 32 + l31];
  }
  float M = fmaxf(fmaxf(ms[0], ms[1]), fmaxf(ms[2], ms[3]));
  float W[SPLITS], Ltot = 0.f;
  #pragma unroll
  for (int sp = 0; sp < SPLITS; ++sp) {
    W[sp] = __builtin_amdgcn_exp2f(ms[sp] - M);
    Ltot += W[sp] * Ls[sp];
  }
  const float rL = 1.f / Ltot;
  float* Orow = Out + (size_t)(b * NS + qb + l31) * NE + wv * 32;
  #pragma unroll
  for (int rq = 0; rq < 4; ++rq) {
    float4 acc = make_float4(0.f, 0.f, 0.f, 0.f);
    #pragma unroll
    for (int sp = 0; sp < SPLITS; ++sp) {
      float4 v = *(const float4*)(smO + (size_t)((sp * 4 + wv) * 64 + lane) * 16 + rq * 4);
      acc.x += W[sp] * v.x; acc.y += W[sp] * v.y;
      acc.z += W[sp] * v.z; acc.w += W[sp] * v.w;
    }
    acc.x *= rL; acc.y *= rL; acc.z *= rL; acc.w *= rL;
    // e = wv*32 + 8*rq + 4*hi + 0..3  (C/D row map of 32x32)
    *(float4*)(Orow + 8 * rq + 4 * hi) = acc;
  }
}

extern "C" void kernel_launch(void* const* d_in, const int* in_sizes, int n_in,
                              void* d_out, int out_size, void* d_ws, size_t ws_size,
                              hipStream_t stream) {
  const float* X  = (const float*)d_in[0];
  // d_in[1] = context : unused (per-row bias is softmax-invariant)
  const float* Wq = (const float*)d_in[2];
  const float* bq = (const float*)d_in[3];
  const float* Wk = (const float*)d_in[4];
  const float* bk = (const float*)d_in[5];
  const float* Wv = (const float*)d_in[6];
  const float* bv = (const float*)d_in[7];
  // d_in[8] = Wc, d_in[9] = bc : unused

  unsigned short* Qs  = (unsigned short*)d_ws;                // 4 MB
  unsigned short* Kd  = Qs + (size_t)NB * NS * NE;            // 4 MB (staged)
  unsigned short* VT  = Kd + (size_t)NB * NS * NE;            // 4 MB (staged)
  unsigned short* Wqb = VT + (size_t)NB * NS * NE;            // 32 KB x3
  unsigned short* Wkb = Wqb + NE * NE;
  unsigned short* Wvb = Wkb + NE * NE;

  prep_k<<<48, 256, 0, stream>>>(Wq, Wk, Wv, Wqb, Wkb, Wvb);
  qkv_proj_k<<<512, 256, 0, stream>>>(X, Wqb, bq, Wkb, bk, Wvb, bv, Qs, Kd, VT);
  attn_k<<<512, 256, 0, stream>>>(Qs, Kd, VT, (float*)d_out);
}

// Round 12
// 101.717 us; speedup vs baseline: 1.5143x; 1.1041x over previous
//
#include <hip/hip_runtime.h>
#include <hip/hip_bf16.h>

typedef short short8 __attribute__((ext_vector_type(8)));
typedef float f32x4 __attribute__((ext_vector_type(4)));
typedef float f32x16 __attribute__((ext_vector_type(16)));
typedef int int4v __attribute__((ext_vector_type(4)));
typedef unsigned short ushort4v __attribute__((ext_vector_type(4)));

#define NB 4
#define NS 4096
#define NE 128
#define ALPHA 0.1275174468f  /* log2(e)/sqrt(128) */
#define KVB 64                 /* keys per staged tile */
#define NIT (NS / KVB)         /* 64 */
#define SPLITS 4               /* 16-key splits sharing one staged tile */
#define DEFER_THR 8.0f         /* log2 units: P bounded by 2^8 */

static __device__ __forceinline__ unsigned short f2bf(float f) {
  union { float f; unsigned int u; } v; v.f = f;
  unsigned int u = v.u;
  return (unsigned short)((u + 0x7FFFu + ((u >> 16) & 1u)) >> 16);
}

// compiler-emitted v_cvt_pk_bf16_f32 (RNE, low=a high=b)
static __device__ __forceinline__ unsigned int pack2bf(float a, float b) {
  union { __hip_bfloat162 h; unsigned int u; } v;
  v.h = __float22bfloat162_rn(float2{a, b});
  return v.u;
}

static __device__ __forceinline__ void gload_lds16(const unsigned short* g,
                                                   unsigned short* l) {
  __builtin_amdgcn_global_load_lds(
      (const __attribute__((address_space(1))) unsigned int*)g,
      (__attribute__((address_space(3))) unsigned int*)l, 16, 0, 0);
}

// ---------------------------------------------------------------------------
// Staged layouts in ws (per batch, per 64-key tile, 16 groups x 1KB):
//  K group g=jt*4+ks, lane=gg*16+li_k: K[j=t*64+jt*16+li_k][e=ks*32+gg*8+0..7]
//  V group g=et*4+sp, lane=hi*32+l31 : V[j=t*64+sp*16+hi*8+0..7][e=et*32+l31]
// ---------------------------------------------------------------------------

__global__ __launch_bounds__(256) void prep_k(
    const float* __restrict__ Wq, const float* __restrict__ Wk,
    const float* __restrict__ Wv,
    unsigned short* __restrict__ Wqb, unsigned short* __restrict__ Wkb,
    unsigned short* __restrict__ Wvb) {
  int i = blockIdx.x * 256 + threadIdx.x;          // 0..12287
  const float* srcs[3] = {Wq, Wk, Wv};
  unsigned short* dsts[3] = {Wqb, Wkb, Wvb};
  int m = i >> 12, off = (i & 4095) * 4;
  float4 v = *(const float4*)(srcs[m] + off);
  ushort4v o;
  o[0] = f2bf(v.x); o[1] = f2bf(v.y); o[2] = f2bf(v.z); o[3] = f2bf(v.w);
  *(ushort4v*)(dsts[m] + off) = o;
}

static __device__ __forceinline__ f32x4 wtile(const short8 xa[4],
                                              const unsigned short* __restrict__ Wb,
                                              int fb, int g, int li) {
  f32x4 acc = {0.f, 0.f, 0.f, 0.f};
  #pragma unroll
  for (int ks = 0; ks < 4; ++ks) {
    short8 wf = *(const short8*)(Wb + (fb * 16 + li) * NE + ks * 32 + g * 8);
    acc = __builtin_amdgcn_mfma_f32_16x16x32_bf16(xa[ks], wf, acc, 0, 0, 0);
  }
  return acc;
}

// ---------------------------------------------------------------------------
// Kernel 1: fused QKV projection (f32 in; Q row-major, K/V in staged layout).
// ---------------------------------------------------------------------------
__global__ __launch_bounds__(256) void qkv_proj_k(
    const float* __restrict__ X,
    const unsigned short* __restrict__ Wqb, const float* __restrict__ bq,
    const unsigned short* __restrict__ Wkb, const float* __restrict__ bk,
    const unsigned short* __restrict__ Wvb, const float* __restrict__ bv,
    unsigned short* __restrict__ Qs, unsigned short* __restrict__ Kd,
    unsigned short* __restrict__ VT) {
  const int lane = threadIdx.x & 63;
  const int wv   = threadIdx.x >> 6;
  const int tile = (blockIdx.x >> 1) * 4 + wv;   // 0..1023
  const int fb0  = (blockIdx.x & 1) * 4;         // output half
  const int m0   = tile * 16;
  const int g    = lane >> 4, li = lane & 15;

  short8 xa[4];
  #pragma unroll
  for (int ks = 0; ks < 4; ++ks) {
    const float* xp = X + (size_t)(m0 + li) * NE + ks * 32 + g * 8;
    float4 x0 = *(const float4*)xp;
    float4 x1 = *(const float4*)(xp + 4);
    short8 t;
    t[0] = (short)f2bf(x0.x); t[1] = (short)f2bf(x0.y);
    t[2] = (short)f2bf(x0.z); t[3] = (short)f2bf(x0.w);
    t[4] = (short)f2bf(x1.x); t[5] = (short)f2bf(x1.y);
    t[6] = (short)f2bf(x1.z); t[7] = (short)f2bf(x1.w);
    xa[ks] = t;
  }

  const int bb  = m0 >> 12;              // batch
  const int tT  = (m0 & 4095) >> 6;      // 64-key tile within batch
  const int jtT = (m0 >> 4) & 3;         // 16-key subtile (= sp for V)
  const size_t tgbase = ((size_t)(bb * 64 + tT)) * 16;   // group base (x512)

  #pragma unroll
  for (int f2 = 0; f2 < 4; ++f2) {
    const int fb = fb0 + f2;
    // ---- Q (row-major, exp2 units) ----
    f32x4 aq = wtile(xa, Wqb, fb, g, li);
    float biq = bq[fb * 16 + li];
    #pragma unroll
    for (int r = 0; r < 4; ++r)
      Qs[(size_t)(m0 + g * 4 + r) * NE + fb * 16 + li] = f2bf((aq[r] + biq) * ALPHA);
    // ---- K staged ----
    f32x4 ak = wtile(xa, Wkb, fb, g, li);
    float bik = bk[fb * 16 + li];
    unsigned short* kdst = Kd + (tgbase + jtT * 4 + (fb >> 1)) * 512 +
                           ((fb & 1) * 2 + (li >> 3)) * 128 + (li & 7);
    #pragma unroll
    for (int r = 0; r < 4; ++r)
      kdst[(g * 4 + r) * 8] = f2bf(ak[r] + bik);
    // ---- V staged ----
    f32x4 av = wtile(xa, Wvb, fb, g, li);
    float biv = bv[fb * 16 + li];
    ushort4v pv;
    #pragma unroll
    for (int r = 0; r < 4; ++r) pv[r] = f2bf(av[r] + biv);
    *(ushort4v*)(VT + (tgbase + (fb >> 1) * 4 + jtT) * 512 +
                 ((g >> 1) * 32 + (fb & 1) * 16 + li) * 8 + (g & 1) * 4) = pv;
  }
}

// ---------------------------------------------------------------------------
// Kernel 2: flash attention. 512 blocks x 256 threads = 2 blocks/CU.
// Barrier-free wave-private pipeline (r11) + defer-max (T13) + strength-
// reduced addressing (loop-invariant voffsets, literal-curb 2x unroll).
// ---------------------------------------------------------------------------
__global__ __launch_bounds__(256, 2) void attn_k(
    const unsigned short* __restrict__ Qs, const unsigned short* __restrict__ Kd,
    const unsigned short* __restrict__ VT, float* __restrict__ Out) {
  __shared__ __align__(16) unsigned char lds_raw[66560];
  unsigned short* kb_lds = (unsigned short*)lds_raw;           // [2][8192]
  unsigned short* vb_lds = (unsigned short*)(lds_raw + 32768); // [2][8192]
  float*          smML   = (float*)(lds_raw + 65536);          // [4][64]
  float*          smO    = (float*)lds_raw;                    // [4][4][64][16] alias

  const int lane = threadIdx.x & 63;
  const int wv   = threadIdx.x >> 6;             // split / stage group / combine et
  const int bi   = blockIdx.x;                   // 0..511
  const int b    = (bi >> 1) & 3;                // batch tied to XCD pair
  const int within = ((bi >> 3) << 1) | (bi & 1);     // 0..127
  const int qb   = within * 32;                  // q-row base (32 rows/block)
  const int g    = lane >> 4, li = lane & 15;
  const int l31  = lane & 31, hi = lane >> 5;
  const bool qsel = (lane >> 4) & 1;             // q-tile of this lane's o-column

  // Q B-frags for both q-tiles: B[k=e][col=q=li]
  short8 qf[2][4];
  #pragma unroll
  for (int qt = 0; qt < 2; ++qt)
    #pragma unroll
    for (int ks = 0; ks < 4; ++ks)
      qf[qt][ks] = *(const short8*)(Qs + (size_t)(b * NS + qb + qt * 16 + li) * NE +
                                    ks * 32 + g * 8);

  const size_t stbase = (size_t)b * 64 * 16 * 512;   // staged base (shorts)

  // loop-invariant per-lane offsets (shorts)
  const int kvoff = wv * 2048 + lane * 8;   // K: group (wv*4+i_), lane*16B
  const int vvoff = wv * 512 + lane * 8;    // V: group (i_*4+wv), lane*16B
  const unsigned short* kls = kb_lds + kvoff;   // QK ds_read base
  const unsigned short* vls = vb_lds + vvoff;   // PV ds_read base
  unsigned short* kld = kb_lds + wv * 2048;     // K stage LDS dest base
  unsigned short* vld = vb_lds + wv * 512;      // V stage LDS dest base

  f32x16 o[4];
  #pragma unroll
  for (int et = 0; et < 4; ++et)
    #pragma unroll
    for (int r = 0; r < 16; ++r) o[et][r] = 0.f;
  float m0 = -1e30f, m1 = -1e30f, L0 = 0.f, L1 = 0.f;

  const int src01 = (lane & 15) | (lane & 32);
  const int src23 = src01 + 16;

  // 8 gloads per wave per tile; uniform base + invariant voffset + imm group
  #define STAGE(BUF, T)                                                        \
    {                                                                          \
      const unsigned short* kpu = Kd + stbase + (size_t)(T) * 8192 + kvoff;    \
      const unsigned short* vpu = VT + stbase + (size_t)(T) * 8192 + vvoff;    \
      _Pragma("unroll")                                                        \
      for (int i_ = 0; i_ < 4; ++i_)                                           \
        gload_lds16(kpu + i_ * 512, kld + (BUF) * 8192 + i_ * 512);            \
      _Pragma("unroll")                                                        \
      for (int i_ = 0; i_ < 4; ++i_)                                           \
        gload_lds16(vpu + i_ * 2048, vld + (BUF) * 8192 + i_ * 2048);          \
    }

  // one full tile body; CURB is a literal 0/1 -> all LDS offsets immediate
  #define BODY(CURB)                                                           \
  {                                                                            \
    f32x4 s0 = {0.f, 0.f, 0.f, 0.f}, s1 = {0.f, 0.f, 0.f, 0.f};                \
    __builtin_amdgcn_s_setprio(1);                                             \
    _Pragma("unroll")                                                          \
    for (int ks = 0; ks < 4; ++ks) {                                           \
      short8 kfr = *(const short8*)(kls + (CURB) * 8192 + ks * 512);           \
      s0 = __builtin_amdgcn_mfma_f32_16x16x32_bf16(kfr, qf[0][ks], s0, 0,0,0); \
      s1 = __builtin_amdgcn_mfma_f32_16x16x32_bf16(kfr, qf[1][ks], s1, 0,0,0); \
    }                                                                          \
    __builtin_amdgcn_s_setprio(0);                                             \
    float tm0 = fmaxf(fmaxf(s0[0], s0[1]), fmaxf(s0[2], s0[3]));               \
    float tm1 = fmaxf(fmaxf(s1[0], s1[1]), fmaxf(s1[2], s1[3]));               \
    tm0 = fmaxf(tm0, __shfl_xor(tm0, 16));                                     \
    tm1 = fmaxf(tm1, __shfl_xor(tm1, 16));                                     \
    tm0 = fmaxf(tm0, __shfl_xor(tm0, 32));                                     \
    tm1 = fmaxf(tm1, __shfl_xor(tm1, 32));                                     \
    if (__any(fmaxf(tm0 - m0, tm1 - m1) > DEFER_THR)) {                        \
      float mn0 = fmaxf(m0, tm0), c0 = __builtin_amdgcn_exp2f(m0 - mn0);       \
      float mn1 = fmaxf(m1, tm1), c1 = __builtin_amdgcn_exp2f(m1 - mn1);       \
      const float cmy = qsel ? c1 : c0;                                        \
      o[0] = o[0] * cmy; o[1] = o[1] * cmy;                                    \
      o[2] = o[2] * cmy; o[3] = o[3] * cmy;                                    \
      L0 *= c0; L1 *= c1; m0 = mn0; m1 = mn1;                                  \
    }                                                                          \
    float p00 = __builtin_amdgcn_exp2f(s0[0] - m0);                            \
    float p01 = __builtin_amdgcn_exp2f(s0[1] - m0);                            \
    float p02 = __builtin_amdgcn_exp2f(s0[2] - m0);                            \
    float p03 = __builtin_amdgcn_exp2f(s0[3] - m0);                            \
    float p10 = __builtin_amdgcn_exp2f(s1[0] - m1);                            \
    float p11 = __builtin_amdgcn_exp2f(s1[1] - m1);                            \
    float p12 = __builtin_amdgcn_exp2f(s1[2] - m1);                            \
    float p13 = __builtin_amdgcn_exp2f(s1[3] - m1);                            \
    L0 += (p00 + p01) + (p02 + p03);                                           \
    L1 += (p10 + p11) + (p12 + p13);                                           \
    unsigned int pk00 = pack2bf(p00, p01);                                     \
    unsigned int pk01 = pack2bf(p02, p03);                                     \
    unsigned int pk10 = pack2bf(p10, p11);                                     \
    unsigned int pk11 = pack2bf(p12, p13);                                     \
    int ta, tb, w0, w1, w2, w3;                                                \
    ta = __shfl((int)pk00, src01); tb = __shfl((int)pk10, src01);              \
    w0 = qsel ? tb : ta;                                                       \
    ta = __shfl((int)pk01, src01); tb = __shfl((int)pk11, src01);              \
    w1 = qsel ? tb : ta;                                                       \
    ta = __shfl((int)pk00, src23); tb = __shfl((int)pk10, src23);              \
    w2 = qsel ? tb : ta;                                                       \
    ta = __shfl((int)pk01, src23); tb = __shfl((int)pk11, src23);              \
    w3 = qsel ? tb : ta;                                                       \
    union { int4v i4; short8 s8; } pb;                                         \
    pb.i4 = (int4v){w0, w1, w2, w3};                                           \
    __builtin_amdgcn_s_setprio(1);                                             \
    _Pragma("unroll")                                                          \
    for (int et = 0; et < 4; ++et) {                                           \
      short8 vfr = *(const short8*)(vls + (CURB) * 8192 + et * 2048);          \
      o[et] = __builtin_amdgcn_mfma_f32_32x32x16_bf16(vfr, pb.s8, o[et], 0,0,0);\
    }                                                                          \
    __builtin_amdgcn_s_setprio(0);                                             \
  }

  STAGE(0, 0);   // prologue: tile 0 in flight

  #pragma unroll 1
  for (int t2 = 0; t2 < NIT; t2 += 2) {
    // even sub-iter (curb = 0)
    STAGE(1, t2 + 1);
    asm volatile("s_waitcnt vmcnt(8)" ::: "memory");
    __builtin_amdgcn_sched_barrier(0);
    BODY(0)
    // odd sub-iter (curb = 1)
    STAGE(0, (t2 + 2) & (NIT - 1));
    asm volatile("s_waitcnt vmcnt(8)" ::: "memory");
    __builtin_amdgcn_sched_barrier(0);
    BODY(1)
  }

  __syncthreads();   // full drain (wrap-stage) before smO alias reuse

  // ---- epilogue: publish split partials (smO aliases staging region) ----
  L0 += __shfl_xor(L0, 16); L0 += __shfl_xor(L0, 32);
  L1 += __shfl_xor(L1, 16); L1 += __shfl_xor(L1, 32);
  #pragma unroll
  for (int et = 0; et < 4; ++et)
    #pragma unroll
    for (int rq = 0; rq < 4; ++rq) {
      float4 v;
      v.x = o[et][rq * 4 + 0]; v.y = o[et][rq * 4 + 1];
      v.z = o[et][rq * 4 + 2]; v.w = o[et][rq * 4 + 3];
      *(float4*)(smO + (size_t)((wv * 4 + et) * 64 + lane) * 16 + rq * 4) = v;
    }
  if (lane < 16) {
    smML[wv * 64 + lane]      = m0;
    smML[wv * 64 + 16 + lane] = m1;
    smML[wv * 64 + 32 + lane] = L0;
    smML[wv * 64 + 48 + lane] = L1;
  }
  __syncthreads();

  // ---- combine 4 splits: wave wv handles e-block et=wv ----
  float ms[SPLITS], Ls[SPLITS];
  #pragma unroll
  for (int sp = 0; sp < SPLITS; ++sp) {
    ms[sp] = smML[sp * 64 + l31];
    Ls[sp] = smML[sp * 64 + 32 + l31];
  }
  float M = fmaxf(fmaxf(ms[0], ms[1]), fmaxf(ms[2], ms[3]));
  float W[SPLITS], Ltot = 0.f;
  #pragma unroll
  for (int sp = 0; sp < SPLITS; ++sp) {
    W[sp] = __builtin_amdgcn_exp2f(ms[sp] - M);
    Ltot += W[sp] * Ls[sp];
  }
  const float rL = 1.f / Ltot;
  float* Orow = Out + (size_t)(b * NS + qb + l31) * NE + wv * 32;
  #pragma unroll
  for (int rq = 0; rq < 4; ++rq) {
    float4 acc = make_float4(0.f, 0.f, 0.f, 0.f);
    #pragma unroll
    for (int sp = 0; sp < SPLITS; ++sp) {
      float4 v = *(const float4*)(smO + (size_t)((sp * 4 + wv) * 64 + lane) * 16 + rq * 4);
      acc.x += W[sp] * v.x; acc.y += W[sp] * v.y;
      acc.z += W[sp] * v.z; acc.w += W[sp] * v.w;
    }
    acc.x *= rL; acc.y *= rL; acc.z *= rL; acc.w *= rL;
    *(float4*)(Orow + 8 * rq + 4 * hi) = acc;
  }
}

extern "C" void kernel_launch(void* const* d_in, const int* in_sizes, int n_in,
                              void* d_out, int out_size, void* d_ws, size_t ws_size,
                              hipStream_t stream) {
  const float* X  = (const float*)d_in[0];
  // d_in[1] = context : unused (per-row bias is softmax-invariant)
  const float* Wq = (const float*)d_in[2];
  const float* bq = (const float*)d_in[3];
  const float* Wk = (const float*)d_in[4];
  const float* bk = (const float*)d_in[5];
  const float* Wv = (const float*)d_in[6];
  const float* bv = (const float*)d_in[7];
  // d_in[8] = Wc, d_in[9] = bc : unused

  unsigned short* Qs  = (unsigned short*)d_ws;                // 4 MB
  unsigned short* Kd  = Qs + (size_t)NB * NS * NE;            // 4 MB (staged)
  unsigned short* VT  = Kd + (size_t)NB * NS * NE;            // 4 MB (staged)
  unsigned short* Wqb = VT + (size_t)NB * NS * NE;            // 32 KB x3
  unsigned short* Wkb = Wqb + NE * NE;
  unsigned short* Wvb = Wkb + NE * NE;

  prep_k<<<48, 256, 0, stream>>>(Wq, Wk, Wv, Wqb, Wkb, Wvb);
  qkv_proj_k<<<512, 256, 0, stream>>>(X, Wqb, bq, Wkb, bk, Wvb, bv, Qs, Kd, VT);
  attn_k<<<512, 256, 0, stream>>>(Qs, Kd, VT, (float*)d_out);
}

// Round 13
// 84.029 us; speedup vs baseline: 1.8331x; 1.2105x over previous
//
#include <hip/hip_runtime.h>
#include <hip/hip_bf16.h>

typedef short short8 __attribute__((ext_vector_type(8)));
typedef float f32x4 __attribute__((ext_vector_type(4)));
typedef float f32x16 __attribute__((ext_vector_type(16)));
typedef int int4v __attribute__((ext_vector_type(4)));
typedef unsigned short ushort4v __attribute__((ext_vector_type(4)));

#define NB 4
#define NS 4096
#define NE 128
#define ALPHA 0.1275174468f  /* log2(e)/sqrt(128) */
#define KVB 64                 /* keys per tile */
#define NIT (NS / KVB)         /* 64 */
#define SPLITS 4               /* 16-key splits */
#define DEFER_THR 8.0f         /* log2 units: P bounded by 2^8 */

static __device__ __forceinline__ unsigned short f2bf(float f) {
  union { float f; unsigned int u; } v; v.f = f;
  unsigned int u = v.u;
  return (unsigned short)((u + 0x7FFFu + ((u >> 16) & 1u)) >> 16);
}
static __device__ __forceinline__ unsigned int pack2bf(float a, float b) {
  union { __hip_bfloat162 h; unsigned int u; } v;
  v.h = __float22bfloat162_rn(float2{a, b});
  return v.u;
}
static __device__ __forceinline__ short8 as_s8(int4v x) {
  union { int4v i; short8 s; } u; u.i = x; return u.s;
}

// ---------------------------------------------------------------------------
// Staged ws layouts (per batch, per 64-key tile, 16 groups x 1KB, contiguous):
//  K group jt*4+ks, lane=gg*16+li: K[j=jt*16+li][e=ks*32+gg*8+..7]
//  V group sp*4+et, lane=hi*32+l31: V[j=sp*16+hi*8+..7][e=et*32+l31]  (wave-major)
// ---------------------------------------------------------------------------

__global__ __launch_bounds__(256) void prep_k(
    const float* __restrict__ Wq, const float* __restrict__ Wk,
    const float* __restrict__ Wv,
    unsigned short* __restrict__ Wqb, unsigned short* __restrict__ Wkb,
    unsigned short* __restrict__ Wvb) {
  int i = blockIdx.x * 256 + threadIdx.x;
  const float* srcs[3] = {Wq, Wk, Wv};
  unsigned short* dsts[3] = {Wqb, Wkb, Wvb};
  int m = i >> 12, off = (i & 4095) * 4;
  float4 v = *(const float4*)(srcs[m] + off);
  ushort4v o;
  o[0] = f2bf(v.x); o[1] = f2bf(v.y); o[2] = f2bf(v.z); o[3] = f2bf(v.w);
  *(ushort4v*)(dsts[m] + off) = o;
}

static __device__ __forceinline__ f32x4 wtile(const short8 xa[4],
                                              const unsigned short* __restrict__ Wb,
                                              int fb, int g, int li) {
  f32x4 acc = {0.f, 0.f, 0.f, 0.f};
  #pragma unroll
  for (int ks = 0; ks < 4; ++ks) {
    short8 wf = *(const short8*)(Wb + (fb * 16 + li) * NE + ks * 32 + g * 8);
    acc = __builtin_amdgcn_mfma_f32_16x16x32_bf16(xa[ks], wf, acc, 0, 0, 0);
  }
  return acc;
}

// ---------------------------------------------------------------------------
// Kernel 1: fused QKV projection (f32 in; Q row-major, K/V staged layout).
// ---------------------------------------------------------------------------
__global__ __launch_bounds__(256) void qkv_proj_k(
    const float* __restrict__ X,
    const unsigned short* __restrict__ Wqb, const float* __restrict__ bq,
    const unsigned short* __restrict__ Wkb, const float* __restrict__ bk,
    const unsigned short* __restrict__ Wvb, const float* __restrict__ bv,
    unsigned short* __restrict__ Qs, unsigned short* __restrict__ Kd,
    unsigned short* __restrict__ VT) {
  const int lane = threadIdx.x & 63;
  const int wv   = threadIdx.x >> 6;
  const int tile = (blockIdx.x >> 1) * 4 + wv;   // 0..1023
  const int fb0  = (blockIdx.x & 1) * 4;         // output half
  const int m0   = tile * 16;
  const int g    = lane >> 4, li = lane & 15;

  short8 xa[4];
  #pragma unroll
  for (int ks = 0; ks < 4; ++ks) {
    const float* xp = X + (size_t)(m0 + li) * NE + ks * 32 + g * 8;
    float4 x0 = *(const float4*)xp;
    float4 x1 = *(const float4*)(xp + 4);
    short8 t;
    t[0] = (short)f2bf(x0.x); t[1] = (short)f2bf(x0.y);
    t[2] = (short)f2bf(x0.z); t[3] = (short)f2bf(x0.w);
    t[4] = (short)f2bf(x1.x); t[5] = (short)f2bf(x1.y);
    t[6] = (short)f2bf(x1.z); t[7] = (short)f2bf(x1.w);
    xa[ks] = t;
  }

  const int bb  = m0 >> 12;              // batch
  const int tT  = (m0 & 4095) >> 6;      // 64-key tile within batch
  const int jtT = (m0 >> 4) & 3;         // 16-key subtile (= sp)
  const size_t tgbase = ((size_t)(bb * 64 + tT)) * 16;   // group base (x512)

  #pragma unroll
  for (int f2 = 0; f2 < 4; ++f2) {
    const int fb = fb0 + f2;
    // ---- Q ----
    f32x4 aq = wtile(xa, Wqb, fb, g, li);
    float biq = bq[fb * 16 + li];
    #pragma unroll
    for (int r = 0; r < 4; ++r)
      Qs[(size_t)(m0 + g * 4 + r) * NE + fb * 16 + li] = f2bf((aq[r] + biq) * ALPHA);
    // ---- K staged: group jtT*4 + (fb>>1)... (unchanged r9 layout) ----
    f32x4 ak = wtile(xa, Wkb, fb, g, li);
    float bik = bk[fb * 16 + li];
    unsigned short* kdst = Kd + (tgbase + jtT * 4 + (fb >> 1)) * 512 +
                           ((fb & 1) * 2 + (li >> 3)) * 128 + (li & 7);
    #pragma unroll
    for (int r = 0; r < 4; ++r)
      kdst[(g * 4 + r) * 8] = f2bf(ak[r] + bik);
    // ---- V staged: group index now WAVE-MAJOR = jtT*4 + (fb>>1) ----
    f32x4 av = wtile(xa, Wvb, fb, g, li);
    float biv = bv[fb * 16 + li];
    ushort4v pv;
    #pragma unroll
    for (int r = 0; r < 4; ++r) pv[r] = f2bf(av[r] + biv);
    *(ushort4v*)(VT + (tgbase + jtT * 4 + (fb >> 1)) * 512 +
                 ((g >> 1) * 32 + (fb & 1) * 16 + li) * 8 + (g & 1) * 4) = pv;
  }
}

// ---------------------------------------------------------------------------
// Kernel 2: flash attention. 512 blocks x 256 threads = 2 blocks/CU.
// NO LDS in the main loop: K/V fragments loaded straight to VGPRs via
// asm-volatile global_load_dwordx4 (contiguous lane*16B bursts), register
// double-buffered, manual counted vmcnt(8). DS pipe carries only the 8
// P-exchange shuffles. LDS used only for the final 4-split combine.
// ---------------------------------------------------------------------------
__global__ __launch_bounds__(256, 2) void attn_k(
    const unsigned short* __restrict__ Qs, const unsigned short* __restrict__ Kd,
    const unsigned short* __restrict__ VT, float* __restrict__ Out) {
  __shared__ float smO[SPLITS * 4 * 64 * 16];   // 64 KB
  __shared__ float smML[SPLITS * 64];           // 1 KB

  const int lane = threadIdx.x & 63;
  const int wv   = threadIdx.x >> 6;             // split / combine et
  const int bi   = blockIdx.x;                   // 0..511
  const int b    = (bi >> 1) & 3;                // batch tied to XCD pair
  const int within = ((bi >> 3) << 1) | (bi & 1);     // 0..127
  const int qb   = within * 32;                  // q-row base
  const int g    = lane >> 4, li = lane & 15;
  const int l31  = lane & 31, hi = lane >> 5;
  const bool qsel = (lane >> 4) & 1;

  // ---- Q B-frags via asm loads (keeps compiler out of the vmcnt domain) ----
  int4v q00, q01, q02, q03, q10, q11, q12, q13;
  {
    const unsigned short* q0 = Qs + (size_t)(b * NS + qb + li) * NE + g * 8;
    const unsigned short* q1 = Qs + (size_t)(b * NS + qb + 16 + li) * NE + g * 8;
    unsigned long long a0 = (unsigned long long)q0, a1 = (unsigned long long)q1;
    asm volatile("global_load_dwordx4 %0, %1, off"             : "=v"(q00) : "v"(a0));
    asm volatile("global_load_dwordx4 %0, %1, off offset:64"   : "=v"(q01) : "v"(a0));
    asm volatile("global_load_dwordx4 %0, %1, off offset:128"  : "=v"(q02) : "v"(a0));
    asm volatile("global_load_dwordx4 %0, %1, off offset:192"  : "=v"(q03) : "v"(a0));
    asm volatile("global_load_dwordx4 %0, %1, off"             : "=v"(q10) : "v"(a1));
    asm volatile("global_load_dwordx4 %0, %1, off offset:64"   : "=v"(q11) : "v"(a1));
    asm volatile("global_load_dwordx4 %0, %1, off offset:128"  : "=v"(q12) : "v"(a1));
    asm volatile("global_load_dwordx4 %0, %1, off offset:192"  : "=v"(q13) : "v"(a1));
  }

  const size_t stbase = (size_t)b * 64 * 16 * 512;       // shorts
  const int    kvoff  = wv * 2048 + lane * 8;            // shorts
  const unsigned long long kbase =
      (unsigned long long)(Kd + stbase + kvoff);
  const unsigned long long vbase =
      (unsigned long long)(VT + stbase + kvoff);

  // register tiles: two sets (A/B), 4 K + 4 V frags each
  int4v ka0, ka1, ka2, ka3, va0, va1, va2, va3;
  int4v kb0, kb1, kb2, kb3, vb0, vb1, vb2, vb3;

  #define LOAD_SET(K0,K1,K2,K3,V0,V1,V2,V3,T)                                   \
    {                                                                           \
      unsigned long long ka_ = kbase + (unsigned long long)(T) * 16384;         \
      unsigned long long va_ = vbase + (unsigned long long)(T) * 16384;         \
      asm volatile("global_load_dwordx4 %0, %1, off"             : "=v"(K0) : "v"(ka_)); \
      asm volatile("global_load_dwordx4 %0, %1, off offset:1024" : "=v"(K1) : "v"(ka_)); \
      asm volatile("global_load_dwordx4 %0, %1, off offset:2048" : "=v"(K2) : "v"(ka_)); \
      asm volatile("global_load_dwordx4 %0, %1, off offset:3072" : "=v"(K3) : "v"(ka_)); \
      asm volatile("global_load_dwordx4 %0, %1, off"             : "=v"(V0) : "v"(va_)); \
      asm volatile("global_load_dwordx4 %0, %1, off offset:1024" : "=v"(V1) : "v"(va_)); \
      asm volatile("global_load_dwordx4 %0, %1, off offset:2048" : "=v"(V2) : "v"(va_)); \
      asm volatile("global_load_dwordx4 %0, %1, off offset:3072" : "=v"(V3) : "v"(va_)); \
    }
  #define LOAD_A(T) LOAD_SET(ka0,ka1,ka2,ka3,va0,va1,va2,va3,T)
  #define LOAD_B(T) LOAD_SET(kb0,kb1,kb2,kb3,vb0,vb1,vb2,vb3,T)
  #define WAIT8 asm volatile("s_waitcnt vmcnt(8)" ::: "memory"); \
                __builtin_amdgcn_sched_barrier(0);

  f32x16 o[4];
  #pragma unroll
  for (int et = 0; et < 4; ++et)
    #pragma unroll
    for (int r = 0; r < 16; ++r) o[et][r] = 0.f;
  float m0 = -1e30f, m1 = -1e30f, L0 = 0.f, L1 = 0.f;

  const int src01 = (lane & 15) | (lane & 32);
  const int src23 = src01 + 16;

  #define BODY(K0,K1,K2,K3,V0,V1,V2,V3)                                        \
  {                                                                            \
    f32x4 s0 = {0.f, 0.f, 0.f, 0.f}, s1 = {0.f, 0.f, 0.f, 0.f};                \
    short8 qa0 = as_s8(q00), qa1 = as_s8(q01), qa2 = as_s8(q02), qa3 = as_s8(q03); \
    short8 qb0_ = as_s8(q10), qb1_ = as_s8(q11), qb2_ = as_s8(q12), qb3_ = as_s8(q13); \
    __builtin_amdgcn_s_setprio(1);                                             \
    s0 = __builtin_amdgcn_mfma_f32_16x16x32_bf16(as_s8(K0), qa0, s0, 0,0,0);   \
    s1 = __builtin_amdgcn_mfma_f32_16x16x32_bf16(as_s8(K0), qb0_, s1, 0,0,0);  \
    s0 = __builtin_amdgcn_mfma_f32_16x16x32_bf16(as_s8(K1), qa1, s0, 0,0,0);   \
    s1 = __builtin_amdgcn_mfma_f32_16x16x32_bf16(as_s8(K1), qb1_, s1, 0,0,0);  \
    s0 = __builtin_amdgcn_mfma_f32_16x16x32_bf16(as_s8(K2), qa2, s0, 0,0,0);   \
    s1 = __builtin_amdgcn_mfma_f32_16x16x32_bf16(as_s8(K2), qb2_, s1, 0,0,0);  \
    s0 = __builtin_amdgcn_mfma_f32_16x16x32_bf16(as_s8(K3), qa3, s0, 0,0,0);   \
    s1 = __builtin_amdgcn_mfma_f32_16x16x32_bf16(as_s8(K3), qb3_, s1, 0,0,0);  \
    __builtin_amdgcn_s_setprio(0);                                             \
    float tm0 = fmaxf(fmaxf(s0[0], s0[1]), fmaxf(s0[2], s0[3]));               \
    float tm1 = fmaxf(fmaxf(s1[0], s1[1]), fmaxf(s1[2], s1[3]));               \
    if (__any(fmaxf(tm0 - m0, tm1 - m1) > DEFER_THR)) {                        \
      tm0 = fmaxf(tm0, __shfl_xor(tm0, 16));                                   \
      tm1 = fmaxf(tm1, __shfl_xor(tm1, 16));                                   \
      tm0 = fmaxf(tm0, __shfl_xor(tm0, 32));                                   \
      tm1 = fmaxf(tm1, __shfl_xor(tm1, 32));                                   \
      float mn0 = fmaxf(m0, tm0), c0 = __builtin_amdgcn_exp2f(m0 - mn0);       \
      float mn1 = fmaxf(m1, tm1), c1 = __builtin_amdgcn_exp2f(m1 - mn1);       \
      const float cmy = qsel ? c1 : c0;                                        \
      o[0] = o[0] * cmy; o[1] = o[1] * cmy;                                    \
      o[2] = o[2] * cmy; o[3] = o[3] * cmy;                                    \
      L0 *= c0; L1 *= c1; m0 = mn0; m1 = mn1;                                  \
    }                                                                          \
    float p00 = __builtin_amdgcn_exp2f(s0[0] - m0);                            \
    float p01 = __builtin_amdgcn_exp2f(s0[1] - m0);                            \
    float p02 = __builtin_amdgcn_exp2f(s0[2] - m0);                            \
    float p03 = __builtin_amdgcn_exp2f(s0[3] - m0);                            \
    float p10 = __builtin_amdgcn_exp2f(s1[0] - m1);                            \
    float p11 = __builtin_amdgcn_exp2f(s1[1] - m1);                            \
    float p12 = __builtin_amdgcn_exp2f(s1[2] - m1);                            \
    float p13 = __builtin_amdgcn_exp2f(s1[3] - m1);                            \
    L0 += (p00 + p01) + (p02 + p03);                                           \
    L1 += (p10 + p11) + (p12 + p13);                                           \
    unsigned int pk00 = pack2bf(p00, p01);                                     \
    unsigned int pk01 = pack2bf(p02, p03);                                     \
    unsigned int pk10 = pack2bf(p10, p11);                                     \
    unsigned int pk11 = pack2bf(p12, p13);                                     \
    int ta, tb, w0, w1, w2, w3;                                                \
    ta = __shfl((int)pk00, src01); tb = __shfl((int)pk10, src01);              \
    w0 = qsel ? tb : ta;                                                       \
    ta = __shfl((int)pk01, src01); tb = __shfl((int)pk11, src01);              \
    w1 = qsel ? tb : ta;                                                       \
    ta = __shfl((int)pk00, src23); tb = __shfl((int)pk10, src23);              \
    w2 = qsel ? tb : ta;                                                       \
    ta = __shfl((int)pk01, src23); tb = __shfl((int)pk11, src23);              \
    w3 = qsel ? tb : ta;                                                       \
    union { int4v i4; short8 s8; } pb;                                         \
    pb.i4 = (int4v){w0, w1, w2, w3};                                           \
    __builtin_amdgcn_s_setprio(1);                                             \
    o[0] = __builtin_amdgcn_mfma_f32_32x32x16_bf16(as_s8(V0), pb.s8, o[0], 0,0,0); \
    o[1] = __builtin_amdgcn_mfma_f32_32x32x16_bf16(as_s8(V1), pb.s8, o[1], 0,0,0); \
    o[2] = __builtin_amdgcn_mfma_f32_32x32x16_bf16(as_s8(V2), pb.s8, o[2], 0,0,0); \
    o[3] = __builtin_amdgcn_mfma_f32_32x32x16_bf16(as_s8(V3), pb.s8, o[3], 0,0,0); \
    __builtin_amdgcn_s_setprio(0);                                             \
  }

  // prologue: Q (8 loads) + tile 0 (8 loads); wait so only tile0's 8 remain
  LOAD_A(0);
  WAIT8;   // Q frags ready; tile 0 in flight

  #pragma unroll 1
  for (int t2 = 0; t2 < NIT; t2 += 2) {
    LOAD_B(t2 + 1);
    WAIT8;   // tile t2 (set A) landed; set B in flight
    BODY(ka0, ka1, ka2, ka3, va0, va1, va2, va3)
    LOAD_A((t2 + 2) & (NIT - 1));
    WAIT8;   // tile t2+1 (set B) landed; set A in flight
    BODY(kb0, kb1, kb2, kb3, vb0, vb1, vb2, vb3)
  }

  __syncthreads();

  // ---- epilogue: publish split partials ----
  L0 += __shfl_xor(L0, 16); L0 += __shfl_xor(L0, 32);
  L1 += __shfl_xor(L1, 16); L1 += __shfl_xor(L1, 32);
  #pragma unroll
  for (int et = 0; et < 4; ++et)
    #pragma unroll
    for (int rq = 0; rq < 4; ++rq) {
      float4 v;
      v.x = o[et][rq * 4 + 0]; v.y = o[et][rq * 4 + 1];
      v.z = o[et][rq * 4 + 2]; v.w = o[et][rq * 4 + 3];
      *(float4*)(smO + (size_t)((wv * 4 + et) * 64 + lane) * 16 + rq * 4) = v;
    }
  if (lane < 16) {
    smML[wv * 64 + lane]      = m0;
    smML[wv * 64 + 16 + lane] = m1;
    smML[wv * 64 + 32 + lane] = L0;
    smML[wv * 64 + 48 + lane] = L1;
  }
  __syncthreads();

  // ---- combine 4 splits: wave wv handles e-block et=wv ----
  float ms[SPLITS], Ls[SPLITS];
  #pragma unroll
  for (int sp = 0; sp < SPLITS; ++sp) {
    ms[sp] = smML[sp * 64 + l31];
    Ls[sp] = smML[sp * 64 + 32 + l31];
  }
  float M = fmaxf(fmaxf(ms[0], ms[1]), fmaxf(ms[2], ms[3]));
  float W[SPLITS], Ltot = 0.f;
  #pragma unroll
  for (int sp = 0; sp < SPLITS; ++sp) {
    W[sp] = __builtin_amdgcn_exp2f(ms[sp] - M);
    Ltot += W[sp] * Ls[sp];
  }
  const float rL = 1.f / Ltot;
  float* Orow = Out + (size_t)(b * NS + qb + l31) * NE + wv * 32;
  #pragma unroll
  for (int rq = 0; rq < 4; ++rq) {
    float4 acc = make_float4(0.f, 0.f, 0.f, 0.f);
    #pragma unroll
    for (int sp = 0; sp < SPLITS; ++sp) {
      float4 v = *(const float4*)(smO + (size_t)((sp * 4 + wv) * 64 + lane) * 16 + rq * 4);
      acc.x += W[sp] * v.x; acc.y += W[sp] * v.y;
      acc.z += W[sp] * v.z; acc.w += W[sp] * v.w;
    }
    acc.x *= rL; acc.y *= rL; acc.z *= rL; acc.w *= rL;
    *(float4*)(Orow + 8 * rq + 4 * hi) = acc;
  }
}

extern "C" void kernel_launch(void* const* d_in, const int* in_sizes, int n_in,
                              void* d_out, int out_size, void* d_ws, size_t ws_size,
                              hipStream_t stream) {
  const float* X  = (const float*)d_in[0];
  // d_in[1] = context : unused (per-row bias is softmax-invariant)
  const float* Wq = (const float*)d_in[2];
  const float* bq = (const float*)d_in[3];
  const float* Wk = (const float*)d_in[4];
  const float* bk = (const float*)d_in[5];
  const float* Wv = (const float*)d_in[6];
  const float* bv = (const float*)d_in[7];
  // d_in[8] = Wc, d_in[9] = bc : unused

  unsigned short* Qs  = (unsigned short*)d_ws;                // 4 MB
  unsigned short* Kd  = Qs + (size_t)NB * NS * NE;            // 4 MB (staged)
  unsigned short* VT  = Kd + (size_t)NB * NS * NE;            // 4 MB (staged)
  unsigned short* Wqb = VT + (size_t)NB * NS * NE;            // 32 KB x3
  unsigned short* Wkb = Wqb + NE * NE;
  unsigned short* Wvb = Wkb + NE * NE;

  prep_k<<<48, 256, 0, stream>>>(Wq, Wk, Wv, Wqb, Wkb, Wvb);
  qkv_proj_k<<<512, 256, 0, stream>>>(X, Wqb, bq, Wkb, bk, Wvb, bv, Qs, Kd, VT);
  attn_k<<<512, 256, 0, stream>>>(Qs, Kd, VT, (float*)d_out);
}